// Round 1
// baseline (2301.994 us; speedup 1.0000x reference)
//
#include <hip/hip_runtime.h>
#include <math.h>

#define D_MODEL 1024
#define NH 16
#define HD 64
#define SEQ 2048
#define BATCH 2
#define MROWS (BATCH*SEQ)   // 4096
#define KDIM 1024

// ---------------------------------------------------------------------------
// Tiled fp32 GEMM: C[M,N] = A[M,K] @ W^T (W is [N,K] row-major) + bias[N]
// MODE 0: out[m*N + n]                         (plain row-major)
// MODE 1: out[((b*NH+h)*SEQ+s)*HD + d]         (QKV head-major layout)
//         where b = m/SEQ, s = m%SEQ, h = n/HD, d = n%HD
// Block: 256 threads, 64x64 tile, 4x4 register blocking, BK=16.
// ---------------------------------------------------------------------------
template<int MODE>
__global__ __launch_bounds__(256)
void gemm_bias(const float* __restrict__ A,
               const float* __restrict__ W,
               const float* __restrict__ bias,
               float* __restrict__ out) {
    __shared__ float As[16][65];
    __shared__ float Bs[16][65];
    const int t  = threadIdx.x;
    const int m0 = blockIdx.x * 64;
    const int n0 = blockIdx.y * 64;
    const int tm = (t >> 4) * 4;
    const int tn = (t & 15) * 4;
    float acc[4][4] = {};

    for (int k0 = 0; k0 < KDIM; k0 += 16) {
        #pragma unroll
        for (int i = 0; i < 4; i++) {
            int idx = t + i * 256;          // 0..1023
            int kk  = idx & 15;
            int mm  = idx >> 4;             // 0..63
            As[kk][mm] = A[(size_t)(m0 + mm) * KDIM + k0 + kk];
            Bs[kk][mm] = W[(size_t)(n0 + mm) * KDIM + k0 + kk];
        }
        __syncthreads();
        #pragma unroll
        for (int kk = 0; kk < 16; kk++) {
            float a[4], b[4];
            #pragma unroll
            for (int i = 0; i < 4; i++) a[i] = As[kk][tm + i];
            #pragma unroll
            for (int j = 0; j < 4; j++) b[j] = Bs[kk][tn + j];
            #pragma unroll
            for (int i = 0; i < 4; i++)
                #pragma unroll
                for (int j = 0; j < 4; j++)
                    acc[i][j] += a[i] * b[j];
        }
        __syncthreads();
    }

    #pragma unroll
    for (int i = 0; i < 4; i++) {
        #pragma unroll
        for (int j = 0; j < 4; j++) {
            int m = m0 + tm + i;
            int n = n0 + tn + j;
            float v = acc[i][j] + bias[n];
            if (MODE == 0) {
                out[(size_t)m * 1024 + n] = v;
            } else {
                int b = m >> 11;        // m / SEQ
                int s = m & 2047;       // m % SEQ
                int h = n >> 6;         // n / HD
                int d = n & 63;         // n % HD
                out[((((size_t)b * NH + h) * SEQ + s) << 6) + d] = v;
            }
        }
    }
}

// ---------------------------------------------------------------------------
// RoPE (in place) on a [B*NH, SEQ, HD] tensor. One thread per (bh, s, d<32) pair.
// q'[d]    = q[d]*cos(s*inv_f[d])    - q[d+32]*sin(s*inv_f[d])
// q'[d+32] = q[d+32]*cos(s*inv_f[d]) + q[d]*sin(s*inv_f[d])
// ---------------------------------------------------------------------------
__global__ __launch_bounds__(256)
void rope_kernel(float* __restrict__ X) {
    int idx = blockIdx.x * blockDim.x + threadIdx.x;
    const int total = BATCH * NH * SEQ * 32;
    if (idx >= total) return;
    int d  = idx & 31;
    int s  = (idx >> 5) & 2047;
    int bh = idx >> 16;
    size_t base = ((size_t)bh * SEQ + s) * HD;
    float inv = powf(10000.0f, -(float)d * (1.0f / 32.0f));
    float ang = (float)s * inv;
    float c = cosf(ang);
    float sn = sinf(ang);
    float x1 = X[base + d];
    float x2 = X[base + d + 32];
    X[base + d]      = x1 * c - x2 * sn;
    X[base + d + 32] = x2 * c + x1 * sn;
}

// ---------------------------------------------------------------------------
// Flash-style attention, fp32. Q,K,V in [B*NH, SEQ, HD]. One block per
// (32-query tile, bh). Online softmax; O accumulator in registers
// (thread t owns row r = t/8, cols (t%8)*8 .. +8).
// Output written in [B, S, NH, HD] layout (i.e. [B*S, D] for the out-proj).
// ---------------------------------------------------------------------------
__global__ __launch_bounds__(256)
void flash_attn(const float* __restrict__ Q,
                const float* __restrict__ K,
                const float* __restrict__ V,
                float* __restrict__ O) {
    __shared__ float Qs[32][65];
    __shared__ float Ks[32][65];
    __shared__ float Vs[32][65];
    __shared__ float Ps[32][33];
    __shared__ float mS[32], lS[32], aS[32];

    const int t  = threadIdx.x;
    const int q0 = blockIdx.x * 32;
    const int bh = blockIdx.y;
    const size_t baseQ  = ((size_t)bh * SEQ + q0) * HD;
    const size_t baseKV = (size_t)bh * SEQ * HD;

    #pragma unroll
    for (int i = 0; i < 8; i++) {
        int idx = t * 8 + i;                 // 0..2047
        Qs[idx >> 6][idx & 63] = Q[baseQ + idx];
    }
    if (t < 32) { mS[t] = -1e30f; lS[t] = 0.0f; }
    const int r = t >> 3;
    const int g = t & 7;
    float o[8] = {};
    __syncthreads();

    for (int k0 = 0; k0 < SEQ; k0 += 32) {
        #pragma unroll
        for (int i = 0; i < 8; i++) {
            int idx = t * 8 + i;
            Ks[idx >> 6][idx & 63] = K[baseKV + (size_t)k0 * HD + idx];
            Vs[idx >> 6][idx & 63] = V[baseKV + (size_t)k0 * HD + idx];
        }
        __syncthreads();

        // scores: thread computes row r, keys g*4 .. g*4+3
        float sc[4] = {0.f, 0.f, 0.f, 0.f};
        for (int d = 0; d < 64; d++) {
            float qv = Qs[r][d];
            #pragma unroll
            for (int jj = 0; jj < 4; jj++)
                sc[jj] += qv * Ks[g * 4 + jj][d];
        }
        #pragma unroll
        for (int jj = 0; jj < 4; jj++)
            Ps[r][g * 4 + jj] = sc[jj] * 0.125f;   // / sqrt(64)
        __syncthreads();

        // online softmax bookkeeping, one thread per row
        if (t < 32) {
            float mOld = mS[t];
            float mNew = mOld;
            for (int j = 0; j < 32; j++) mNew = fmaxf(mNew, Ps[t][j]);
            float alpha = __expf(mOld - mNew);
            float lsum = 0.0f;
            for (int j = 0; j < 32; j++) {
                float p = __expf(Ps[t][j] - mNew);
                Ps[t][j] = p;
                lsum += p;
            }
            mS[t] = mNew;
            lS[t] = lS[t] * alpha + lsum;
            aS[t] = alpha;
        }
        __syncthreads();

        float alpha = aS[r];
        #pragma unroll
        for (int c = 0; c < 8; c++) o[c] *= alpha;
        for (int kk = 0; kk < 32; kk++) {
            float p = Ps[r][kk];
            #pragma unroll
            for (int c = 0; c < 8; c++)
                o[c] += p * Vs[kk][g * 8 + c];
        }
        __syncthreads();
    }

    float inv_l = 1.0f / lS[r];
    int b = bh >> 4;
    int h = bh & 15;
    int s = q0 + r;
    size_t obase = (((size_t)b * SEQ + s) * NH + h) * HD + g * 8;
    #pragma unroll
    for (int c = 0; c < 8; c++) O[obase + c] = o[c] * inv_l;
}

// ---------------------------------------------------------------------------
extern "C" void kernel_launch(void* const* d_in, const int* in_sizes, int n_in,
                              void* d_out, int out_size, void* d_ws, size_t ws_size,
                              hipStream_t stream) {
    const float* x  = (const float*)d_in[0];
    const float* Wq = (const float*)d_in[1];
    const float* bq = (const float*)d_in[2];
    const float* Wk = (const float*)d_in[3];
    const float* bk = (const float*)d_in[4];
    const float* Wv = (const float*)d_in[5];
    const float* bv = (const float*)d_in[6];
    const float* Wo = (const float*)d_in[7];
    const float* bo = (const float*)d_in[8];
    float* out = (float*)d_out;

    const size_t TEN = (size_t)BATCH * NH * SEQ * HD;   // 4,194,304 floats
    float* Qws  = (float*)d_ws;
    float* Kws  = Qws + TEN;
    float* Vws  = Kws + TEN;
    float* AOws = Vws + TEN;

    dim3 gGemm(MROWS / 64, D_MODEL / 64);   // (64, 16)
    gemm_bias<1><<<gGemm, 256, 0, stream>>>(x, Wq, bq, Qws);
    gemm_bias<1><<<gGemm, 256, 0, stream>>>(x, Wk, bk, Kws);
    gemm_bias<1><<<gGemm, 256, 0, stream>>>(x, Wv, bv, Vws);

    int ropeThreads = BATCH * NH * SEQ * 32;
    rope_kernel<<<ropeThreads / 256, 256, 0, stream>>>(Qws);
    rope_kernel<<<ropeThreads / 256, 256, 0, stream>>>(Kws);

    dim3 gAttn(SEQ / 32, BATCH * NH);        // (64, 32)
    flash_attn<<<gAttn, 256, 0, stream>>>(Qws, Kws, Vws, AOws);

    gemm_bias<0><<<gGemm, 256, 0, stream>>>(AOws, Wo, bo, out);
}

// Round 2
// 1065.678 us; speedup vs baseline: 2.1601x; 2.1601x over previous
//
#include <hip/hip_runtime.h>
#include <math.h>

#define D_MODEL 1024
#define NH 16
#define HD 64
#define SEQ 2048
#define BATCH 2
#define MROWS (BATCH*SEQ)   // 4096
#define KDIM 1024

typedef __attribute__((ext_vector_type(8))) short s8v;   // 8 bf16 (4 VGPRs)
typedef __attribute__((ext_vector_type(4))) float f4v;   // 4 fp32 acc

#define MFMA16(a, b, c) __builtin_amdgcn_mfma_f32_16x16x32_bf16(a, b, c, 0, 0, 0)

__device__ inline unsigned short f32_to_bf16(float f) {
    unsigned u = __float_as_uint(f);
    unsigned r = u + 0x7fffu + ((u >> 16) & 1u);   // RNE
    return (unsigned short)(r >> 16);
}
__device__ inline float bf16_to_f32(unsigned short h) {
    return __uint_as_float(((unsigned)h) << 16);
}

// ---------------------------------------------------------------------------
// Tiled fp32 GEMM: C[M,N] = A[M,K] @ W^T (W is [N,K] row-major) + bias[N]
// MODE 0: out[m*N + n]; MODE 1: out[((b*NH+h)*SEQ+s)*HD + d]
// ---------------------------------------------------------------------------
template<int MODE>
__global__ __launch_bounds__(256)
void gemm_bias(const float* __restrict__ A,
               const float* __restrict__ W,
               const float* __restrict__ bias,
               float* __restrict__ out) {
    __shared__ float As[16][65];
    __shared__ float Bs[16][65];
    const int t  = threadIdx.x;
    const int m0 = blockIdx.x * 64;
    const int n0 = blockIdx.y * 64;
    const int tm = (t >> 4) * 4;
    const int tn = (t & 15) * 4;
    float acc[4][4] = {};

    for (int k0 = 0; k0 < KDIM; k0 += 16) {
        #pragma unroll
        for (int i = 0; i < 4; i++) {
            int idx = t + i * 256;
            int kk  = idx & 15;
            int mm  = idx >> 4;
            As[kk][mm] = A[(size_t)(m0 + mm) * KDIM + k0 + kk];
            Bs[kk][mm] = W[(size_t)(n0 + mm) * KDIM + k0 + kk];
        }
        __syncthreads();
        #pragma unroll
        for (int kk = 0; kk < 16; kk++) {
            float a[4], b[4];
            #pragma unroll
            for (int i = 0; i < 4; i++) a[i] = As[kk][tm + i];
            #pragma unroll
            for (int j = 0; j < 4; j++) b[j] = Bs[kk][tn + j];
            #pragma unroll
            for (int i = 0; i < 4; i++)
                #pragma unroll
                for (int j = 0; j < 4; j++)
                    acc[i][j] += a[i] * b[j];
        }
        __syncthreads();
    }

    #pragma unroll
    for (int i = 0; i < 4; i++) {
        #pragma unroll
        for (int j = 0; j < 4; j++) {
            int m = m0 + tm + i;
            int n = n0 + tn + j;
            float v = acc[i][j] + bias[n];
            if (MODE == 0) {
                out[(size_t)m * 1024 + n] = v;
            } else {
                int b = m >> 11;
                int s = m & 2047;
                int h = n >> 6;
                int d = n & 63;
                out[((((size_t)b * NH + h) * SEQ + s) << 6) + d] = v;
            }
        }
    }
}

// ---------------------------------------------------------------------------
// RoPE (in place) on [B*NH, SEQ, HD]
// ---------------------------------------------------------------------------
__global__ __launch_bounds__(256)
void rope_kernel(float* __restrict__ X) {
    int idx = blockIdx.x * blockDim.x + threadIdx.x;
    const int total = BATCH * NH * SEQ * 32;
    if (idx >= total) return;
    int d  = idx & 31;
    int s  = (idx >> 5) & 2047;
    int bh = idx >> 16;
    size_t base = ((size_t)bh * SEQ + s) * HD;
    float inv = powf(10000.0f, -(float)d * (1.0f / 32.0f));
    float ang = (float)s * inv;
    float c = cosf(ang);
    float sn = sinf(ang);
    float x1 = X[base + d];
    float x2 = X[base + d + 32];
    X[base + d]      = x1 * c - x2 * sn;
    X[base + d + 32] = x2 * c + x1 * sn;
}

// ---------------------------------------------------------------------------
// MFMA flash attention, split-bf16 (hi/lo) arithmetic ~= fp32 accuracy.
// Q,K,V fp32 in [B*NH, SEQ, HD]. Block: 256 thr (4 waves), Q-tile 64 rows
// (wave w owns rows w*16..w*16+15), K-tile 32 keys per iteration.
// 16x16x32 bf16 MFMA. A-frag: A[m=lane&15][k=quad*8+j]. C/D: col=lane&15,
// row=quad*4+reg (verified m89/m120). P round-trips LDS per-wave-private.
// Output -> [B, S, NH, HD].
// ---------------------------------------------------------------------------
__global__ __launch_bounds__(256)
void flash_attn(const float* __restrict__ Q,
                const float* __restrict__ Kg,
                const float* __restrict__ Vg,
                float* __restrict__ O) {
    // K tiles: 32 keys x 64 d, row stride 72 bf16 (144 B = 9*16, 2-way banks)
    __shared__ __align__(16) unsigned short KhS[32 * 72];
    __shared__ __align__(16) unsigned short KlS[32 * 72];
    // V transposed: 64 dims x 32 keys, stride 40, key-col XOR-swizzled by dim
    __shared__ __align__(16) unsigned short VthS[64 * 40];
    __shared__ __align__(16) unsigned short VtlS[64 * 40];
    // P: 64 q-rows x 32 keys, stride 40, col XOR-swizzled by row bit3
    __shared__ __align__(16) unsigned short PhS[64 * 40];
    __shared__ __align__(16) unsigned short PlS[64 * 40];

    const int t    = threadIdx.x;
    const int w    = t >> 6;        // wave 0..3
    const int lane = t & 63;
    const int quad = lane >> 4;     // 0..3
    const int l15  = lane & 15;

    const int q0 = blockIdx.x * 64;
    const int bh = blockIdx.y;
    const size_t kvbase = (size_t)bh * SEQ * HD;

    // ---- Q fragments in registers (held for whole kernel), hi/lo split ----
    s8v qh[2], ql[2];
    {
        const float* qp = Q + kvbase + (size_t)(q0 + w * 16 + l15) * HD + quad * 8;
        #pragma unroll
        for (int st = 0; st < 2; st++) {
            float4 a = *(const float4*)(qp + st * 32);
            float4 b = *(const float4*)(qp + st * 32 + 4);
            float x[8] = {a.x, a.y, a.z, a.w, b.x, b.y, b.z, b.w};
            #pragma unroll
            for (int e = 0; e < 8; e++) {
                unsigned short h = f32_to_bf16(x[e]);
                qh[st][e] = (short)h;
                ql[st][e] = (short)f32_to_bf16(x[e] - bf16_to_f32(h));
            }
        }
    }

    f4v o[4];                        // O accum: 4 d-tiles x 4 rows
    #pragma unroll
    for (int nt = 0; nt < 4; nt++) o[nt] = (f4v){0.f, 0.f, 0.f, 0.f};
    float mprev[4] = {-1e30f, -1e30f, -1e30f, -1e30f};
    float lrun[4]  = {0.f, 0.f, 0.f, 0.f};

    for (int k0 = 0; k0 < SEQ; k0 += 32) {
        __syncthreads();   // protect prev tile's LDS reads

        // ---- stage K tile (fp32 -> hi/lo bf16), [32][72] ----
        {
            int row = t >> 3;               // 0..31
            int dc  = (t & 7) * 8;          // 0..56
            const float* kp = Kg + kvbase + (size_t)(k0 + row) * HD + dc;
            float4 a = *(const float4*)kp;
            float4 b = *(const float4*)(kp + 4);
            float x[8] = {a.x, a.y, a.z, a.w, b.x, b.y, b.z, b.w};
            unsigned base = row * 72 + dc;
            #pragma unroll
            for (int j = 0; j < 4; j++) {
                unsigned short h0 = f32_to_bf16(x[2 * j]);
                unsigned short h1 = f32_to_bf16(x[2 * j + 1]);
                unsigned short l0 = f32_to_bf16(x[2 * j] - bf16_to_f32(h0));
                unsigned short l1 = f32_to_bf16(x[2 * j + 1] - bf16_to_f32(h1));
                *(unsigned*)&KhS[base + 2 * j] = (unsigned)h0 | ((unsigned)h1 << 16);
                *(unsigned*)&KlS[base + 2 * j] = (unsigned)l0 | ((unsigned)l1 << 16);
            }
        }
        // ---- stage V tile transposed (dims x keys), hi/lo, swizzled ----
        {
            int d  = t & 63;
            int sw = ((d >> 3) & 3) << 3;
            #pragma unroll
            for (int ii = 0; ii < 4; ii++) {
                int kp2 = (t >> 6) + ii * 4;     // keypair 0..15
                float v0 = Vg[kvbase + (size_t)(k0 + 2 * kp2)     * HD + d];
                float v1 = Vg[kvbase + (size_t)(k0 + 2 * kp2 + 1) * HD + d];
                unsigned short h0 = f32_to_bf16(v0);
                unsigned short h1 = f32_to_bf16(v1);
                unsigned short l0 = f32_to_bf16(v0 - bf16_to_f32(h0));
                unsigned short l1 = f32_to_bf16(v1 - bf16_to_f32(h1));
                int col = (2 * kp2) ^ sw;        // xor bits 3..4, pair stays adjacent
                *(unsigned*)&VthS[d * 40 + col] = (unsigned)h0 | ((unsigned)h1 << 16);
                *(unsigned*)&VtlS[d * 40 + col] = (unsigned)l0 | ((unsigned)l1 << 16);
            }
        }
        __syncthreads();

        // ---- QK^T: S[16 rows][32 keys] per wave, split-bf16 (3 products) ----
        f4v s0 = (f4v){0.f, 0.f, 0.f, 0.f};
        f4v s1 = (f4v){0.f, 0.f, 0.f, 0.f};
        {
            const unsigned short* kb0 = KhS + (0 * 16 + l15) * 72 + quad * 8;
            const unsigned short* lb0 = KlS + (0 * 16 + l15) * 72 + quad * 8;
            s8v kh0 = *(const s8v*)kb0, kh1 = *(const s8v*)(kb0 + 32);
            s8v kl0 = *(const s8v*)lb0, kl1 = *(const s8v*)(lb0 + 32);
            s0 = MFMA16(qh[0], kh0, s0); s0 = MFMA16(qh[1], kh1, s0);
            s0 = MFMA16(ql[0], kh0, s0); s0 = MFMA16(ql[1], kh1, s0);
            s0 = MFMA16(qh[0], kl0, s0); s0 = MFMA16(qh[1], kl1, s0);
            const unsigned short* kb1 = KhS + (1 * 16 + l15) * 72 + quad * 8;
            const unsigned short* lb1 = KlS + (1 * 16 + l15) * 72 + quad * 8;
            s8v kh2 = *(const s8v*)kb1, kh3 = *(const s8v*)(kb1 + 32);
            s8v kl2 = *(const s8v*)lb1, kl3 = *(const s8v*)(lb1 + 32);
            s1 = MFMA16(qh[0], kh2, s1); s1 = MFMA16(qh[1], kh3, s1);
            s1 = MFMA16(ql[0], kh2, s1); s1 = MFMA16(ql[1], kh3, s1);
            s1 = MFMA16(qh[0], kl2, s1); s1 = MFMA16(qh[1], kl3, s1);
        }

        // ---- online softmax (all in registers; 16-lane shfl reductions) ----
        #pragma unroll
        for (int r = 0; r < 4; r++) {
            float sr0 = s0[r] * 0.125f;
            float sr1 = s1[r] * 0.125f;
            float mt = fmaxf(sr0, sr1);
            mt = fmaxf(mt, __shfl_xor(mt, 1, 64));
            mt = fmaxf(mt, __shfl_xor(mt, 2, 64));
            mt = fmaxf(mt, __shfl_xor(mt, 4, 64));
            mt = fmaxf(mt, __shfl_xor(mt, 8, 64));
            float mnew  = fmaxf(mprev[r], mt);
            float alpha = __expf(mprev[r] - mnew);
            mprev[r] = mnew;
            float p0 = __expf(sr0 - mnew);
            float p1 = __expf(sr1 - mnew);
            float rs = p0 + p1;
            rs += __shfl_xor(rs, 1, 64);
            rs += __shfl_xor(rs, 2, 64);
            rs += __shfl_xor(rs, 4, 64);
            rs += __shfl_xor(rs, 8, 64);
            lrun[r] = lrun[r] * alpha + rs;
            o[0][r] *= alpha; o[1][r] *= alpha; o[2][r] *= alpha; o[3][r] *= alpha;

            // write P hi/lo (per-wave-private rows; swizzle col by row bit3)
            int row_l = w * 16 + quad * 4 + r;
            int cs = row_l & 8;
            int c0 = l15 ^ cs;
            int c1 = (16 + l15) ^ cs;
            unsigned short h = f32_to_bf16(p0);
            PhS[row_l * 40 + c0] = h;
            PlS[row_l * 40 + c0] = f32_to_bf16(p0 - bf16_to_f32(h));
            h = f32_to_bf16(p1);
            PhS[row_l * 40 + c1] = h;
            PlS[row_l * 40 + c1] = f32_to_bf16(p1 - bf16_to_f32(h));
        }

        // ---- PV: O[16 rows][64 dims] per wave, split-bf16 ----
        {
            const int prow = w * 16 + l15;
            const unsigned short* pb = PhS + prow * 40 + ((quad * 8) ^ (prow & 8));
            const unsigned short* plb = PlS + prow * 40 + ((quad * 8) ^ (prow & 8));
            s8v ph = *(const s8v*)pb;
            s8v pl = *(const s8v*)plb;
            #pragma unroll
            for (int nt = 0; nt < 4; nt++) {
                int dim = nt * 16 + l15;
                int voff = dim * 40 + ((quad * 8) ^ (((dim >> 3) & 3) << 3));
                s8v vh = *(const s8v*)&VthS[voff];
                s8v vl = *(const s8v*)&VtlS[voff];
                o[nt] = MFMA16(ph, vh, o[nt]);
                o[nt] = MFMA16(ph, vl, o[nt]);
                o[nt] = MFMA16(pl, vh, o[nt]);
            }
        }
    }

    // ---- epilogue: normalize, write [B, S, NH, HD] ----
    const int b = bh >> 4;
    const int h = bh & 15;
    #pragma unroll
    for (int r = 0; r < 4; r++) {
        float inv_l = 1.0f / lrun[r];
        int s = q0 + w * 16 + quad * 4 + r;
        size_t obase = (((size_t)b * SEQ + s) * NH + h) * HD;
        #pragma unroll
        for (int nt = 0; nt < 4; nt++) {
            O[obase + nt * 16 + l15] = o[nt][r] * inv_l;
        }
    }
}

// ---------------------------------------------------------------------------
extern "C" void kernel_launch(void* const* d_in, const int* in_sizes, int n_in,
                              void* d_out, int out_size, void* d_ws, size_t ws_size,
                              hipStream_t stream) {
    const float* x  = (const float*)d_in[0];
    const float* Wq = (const float*)d_in[1];
    const float* bq = (const float*)d_in[2];
    const float* Wk = (const float*)d_in[3];
    const float* bk = (const float*)d_in[4];
    const float* Wv = (const float*)d_in[5];
    const float* bv = (const float*)d_in[6];
    const float* Wo = (const float*)d_in[7];
    const float* bo = (const float*)d_in[8];
    float* out = (float*)d_out;

    const size_t TEN = (size_t)BATCH * NH * SEQ * HD;
    float* Qws  = (float*)d_ws;
    float* Kws  = Qws + TEN;
    float* Vws  = Kws + TEN;
    float* AOws = Vws + TEN;

    dim3 gGemm(MROWS / 64, D_MODEL / 64);
    gemm_bias<1><<<gGemm, 256, 0, stream>>>(x, Wq, bq, Qws);
    gemm_bias<1><<<gGemm, 256, 0, stream>>>(x, Wk, bk, Kws);
    gemm_bias<1><<<gGemm, 256, 0, stream>>>(x, Wv, bv, Vws);

    int ropeThreads = BATCH * NH * SEQ * 32;
    rope_kernel<<<ropeThreads / 256, 256, 0, stream>>>(Qws);
    rope_kernel<<<ropeThreads / 256, 256, 0, stream>>>(Kws);

    dim3 gAttn(SEQ / 64, BATCH * NH);
    flash_attn<<<gAttn, 256, 0, stream>>>(Qws, Kws, Vws, AOws);

    gemm_bias<0><<<gGemm, 256, 0, stream>>>(AOws, Wo, bo, out);
}

// Round 3
// 670.918 us; speedup vs baseline: 3.4311x; 1.5884x over previous
//
#include <hip/hip_runtime.h>
#include <math.h>

#define D_MODEL 1024
#define NH 16
#define HD 64
#define SEQ 2048
#define BATCH 2
#define MROWS (BATCH*SEQ)   // 4096
#define KDIM 1024

typedef __attribute__((ext_vector_type(8))) short s8v;   // 8 bf16 (4 VGPRs)
typedef __attribute__((ext_vector_type(4))) float f4v;   // 4 fp32 acc

#define MFMA16(a, b, c) __builtin_amdgcn_mfma_f32_16x16x32_bf16(a, b, c, 0, 0, 0)

__device__ __forceinline__ unsigned short f32_to_bf16(float f) {
    unsigned u = __float_as_uint(f);
    unsigned r = u + 0x7fffu + ((u >> 16) & 1u);   // RNE
    return (unsigned short)(r >> 16);
}
__device__ __forceinline__ float bf16_to_f32(unsigned short h) {
    return __uint_as_float(((unsigned)h) << 16);
}

// async global->LDS, 16 B per lane (global_load_lds_dwordx4)
__device__ __forceinline__ void ld16(const unsigned short* g, unsigned short* l) {
    __builtin_amdgcn_global_load_lds(
        (const __attribute__((address_space(1))) void*)g,
        (__attribute__((address_space(3))) void*)l, 16, 0, 0);
}

// ---------------------------------------------------------------------------
// Fused fp32 -> bf16 hi/lo conversion for x (2^20 float4s) + 4 W (2^18 each).
// One float4 per thread; grid = 2^21 threads = 8192 blocks.
// ---------------------------------------------------------------------------
__global__ __launch_bounds__(256)
void convert_hl(const float* __restrict__ x,
                const float* __restrict__ Wq, const float* __restrict__ Wk,
                const float* __restrict__ Wv, const float* __restrict__ Wo,
                unsigned short* __restrict__ xh, unsigned short* __restrict__ xl,
                unsigned short* __restrict__ Wqh, unsigned short* __restrict__ Wql,
                unsigned short* __restrict__ Wkh, unsigned short* __restrict__ Wkl,
                unsigned short* __restrict__ Wvh, unsigned short* __restrict__ Wvl,
                unsigned short* __restrict__ Woh, unsigned short* __restrict__ Wol) {
    int i = blockIdx.x * 256 + threadIdx.x;
    const float* src;
    unsigned short *h, *l;
    int idx;
    if (i < (1 << 20)) {
        src = x; h = xh; l = xl; idx = i;
    } else {
        int j = i - (1 << 20);
        int w = j >> 18;
        idx = j & ((1 << 18) - 1);
        switch (w) {
            case 0:  src = Wq; h = Wqh; l = Wql; break;
            case 1:  src = Wk; h = Wkh; l = Wkl; break;
            case 2:  src = Wv; h = Wvh; l = Wvl; break;
            default: src = Wo; h = Woh; l = Wol; break;
        }
    }
    float4 v = ((const float4*)src)[idx];
    ushort4 hv, lv;
    hv.x = f32_to_bf16(v.x); lv.x = f32_to_bf16(v.x - bf16_to_f32(hv.x));
    hv.y = f32_to_bf16(v.y); lv.y = f32_to_bf16(v.y - bf16_to_f32(hv.y));
    hv.z = f32_to_bf16(v.z); lv.z = f32_to_bf16(v.z - bf16_to_f32(hv.z));
    hv.w = f32_to_bf16(v.w); lv.w = f32_to_bf16(v.w - bf16_to_f32(hv.w));
    ((ushort4*)h)[idx] = hv;
    ((ushort4*)l)[idx] = lv;
}

// ---------------------------------------------------------------------------
// Split-bf16 MFMA GEMM: C[M,N] = Ahl[M,K] @ Whl^T + bias  (~fp32 accuracy)
// A,B given as bf16 hi/lo pairs, row-major [rows][1024].
// 128x128 tile, BK=32, 4 waves (2x2), each wave 64x64 via 4x4 of 16x16x32.
// Staging via global_load_lds width 16 (m97 pattern, row-major [128][32]).
// MODE 0: out[m*1024 + n]                          (plain, out-proj)
// MODE 1: out[((b*NH+h)*SEQ+s)*HD + d]             (V head layout)
// MODE 2: MODE1 layout + fused RoPE                (Q, K)
// ---------------------------------------------------------------------------
template<int MODE>
__global__ __launch_bounds__(256, 2)
void gemm_mfma(const unsigned short* __restrict__ Ah_g,
               const unsigned short* __restrict__ Al_g,
               const unsigned short* __restrict__ Bh_g,
               const unsigned short* __restrict__ Bl_g,
               const float* __restrict__ bias,
               float* __restrict__ out) {
    __shared__ unsigned short Ah[128 * 32];
    __shared__ unsigned short Al[128 * 32];
    __shared__ unsigned short Bh[128 * 32];
    __shared__ unsigned short Bl[128 * 32];

    const int t    = threadIdx.x;
    const int w    = t >> 6;
    const int lane = t & 63;
    const int quad = lane >> 4;
    const int l15  = lane & 15;
    const int wr   = w >> 1;
    const int wc   = w & 1;
    const int m0   = blockIdx.x * 128;
    const int n0   = blockIdx.y * 128;

    // staging coords: 512 lane-slots of 16B per 8KB tile; 4 lanes per row
    const int srow = t >> 2;            // 0..63
    const int scol = (t & 3) * 8;       // bf16 elems
    const unsigned short* agh = Ah_g + (size_t)(m0 + srow) * KDIM + scol;
    const unsigned short* agl = Al_g + (size_t)(m0 + srow) * KDIM + scol;
    const unsigned short* bgh = Bh_g + (size_t)(n0 + srow) * KDIM + scol;
    const unsigned short* bgl = Bl_g + (size_t)(n0 + srow) * KDIM + scol;
    const size_t rstep = (size_t)64 * KDIM;   // +64 rows

    f4v acc[4][4];
    #pragma unroll
    for (int i = 0; i < 4; i++)
        #pragma unroll
        for (int j = 0; j < 4; j++)
            acc[i][j] = (f4v){0.f, 0.f, 0.f, 0.f};

    for (int k0 = 0; k0 < KDIM; k0 += 32) {
        ld16(agh + k0,         &Ah[t * 8]);
        ld16(agh + rstep + k0, &Ah[(256 + t) * 8]);
        ld16(agl + k0,         &Al[t * 8]);
        ld16(agl + rstep + k0, &Al[(256 + t) * 8]);
        ld16(bgh + k0,         &Bh[t * 8]);
        ld16(bgh + rstep + k0, &Bh[(256 + t) * 8]);
        ld16(bgl + k0,         &Bl[t * 8]);
        ld16(bgl + rstep + k0, &Bl[(256 + t) * 8]);
        __syncthreads();

        s8v ah[4], al[4], bh[4], bl[4];
        #pragma unroll
        for (int i = 0; i < 4; i++) {
            int ar = (wr * 64 + i * 16 + l15) * 32 + quad * 8;
            ah[i] = *(const s8v*)&Ah[ar];
            al[i] = *(const s8v*)&Al[ar];
            int br = (wc * 64 + i * 16 + l15) * 32 + quad * 8;
            bh[i] = *(const s8v*)&Bh[br];
            bl[i] = *(const s8v*)&Bl[br];
        }
        #pragma unroll
        for (int mt = 0; mt < 4; mt++) {
            #pragma unroll
            for (int nt = 0; nt < 4; nt++) {
                acc[mt][nt] = MFMA16(ah[mt], bh[nt], acc[mt][nt]);
                acc[mt][nt] = MFMA16(ah[mt], bl[nt], acc[mt][nt]);
                acc[mt][nt] = MFMA16(al[mt], bh[nt], acc[mt][nt]);
            }
        }
        __syncthreads();
    }

    // ---- epilogue. C/D: col = l15 (n), row = quad*4 + r (m) ----
    if (MODE == 2) {
        // fused RoPE: pairs (d, d+32) live in acc[mt][nt] / acc[mt][nt+2]
        #pragma unroll
        for (int mt = 0; mt < 4; mt++) {
            #pragma unroll
            for (int r = 0; r < 4; r++) {
                int m = m0 + wr * 64 + mt * 16 + quad * 4 + r;
                int b = m >> 11;
                int s = m & 2047;
                #pragma unroll
                for (int nt = 0; nt < 2; nt++) {
                    int n1 = n0 + wc * 64 + nt * 16 + l15;
                    int dd = n1 & 31;
                    float v1 = acc[mt][nt][r]     + bias[n1];
                    float v2 = acc[mt][nt + 2][r] + bias[n1 + 32];
                    float inv = powf(10000.0f, -(float)dd * (1.0f / 32.0f));
                    float ang = (float)s * inv;
                    float c  = cosf(ang);
                    float sn = sinf(ang);
                    int h = n1 >> 6;
                    int d = n1 & 63;
                    size_t base = (((size_t)b * NH + h) * SEQ + s) << 6;
                    out[base + d]      = v1 * c - v2 * sn;
                    out[base + d + 32] = v2 * c + v1 * sn;
                }
            }
        }
    } else {
        #pragma unroll
        for (int mt = 0; mt < 4; mt++) {
            #pragma unroll
            for (int nt = 0; nt < 4; nt++) {
                int n = n0 + wc * 64 + nt * 16 + l15;
                float bv = bias[n];
                #pragma unroll
                for (int r = 0; r < 4; r++) {
                    int m = m0 + wr * 64 + mt * 16 + quad * 4 + r;
                    float v = acc[mt][nt][r] + bv;
                    if (MODE == 0) {
                        out[(size_t)m * 1024 + n] = v;
                    } else {
                        int b = m >> 11;
                        int s = m & 2047;
                        int h = n >> 6;
                        int d = n & 63;
                        out[((((size_t)b * NH + h) * SEQ + s) << 6) + d] = v;
                    }
                }
            }
        }
    }
}

// ---------------------------------------------------------------------------
// MFMA flash attention, split-bf16 (unchanged core from R2).
// Output written directly as bf16 hi/lo [B*S, 1024] for the out-proj GEMM.
// ---------------------------------------------------------------------------
__global__ __launch_bounds__(256)
void flash_attn(const float* __restrict__ Q,
                const float* __restrict__ Kg,
                const float* __restrict__ Vg,
                unsigned short* __restrict__ AOh,
                unsigned short* __restrict__ AOl) {
    __shared__ __align__(16) unsigned short KhS[32 * 72];
    __shared__ __align__(16) unsigned short KlS[32 * 72];
    __shared__ __align__(16) unsigned short VthS[64 * 40];
    __shared__ __align__(16) unsigned short VtlS[64 * 40];
    __shared__ __align__(16) unsigned short PhS[64 * 40];
    __shared__ __align__(16) unsigned short PlS[64 * 40];

    const int t    = threadIdx.x;
    const int w    = t >> 6;
    const int lane = t & 63;
    const int quad = lane >> 4;
    const int l15  = lane & 15;

    const int q0 = blockIdx.x * 64;
    const int bh = blockIdx.y;
    const size_t kvbase = (size_t)bh * SEQ * HD;

    s8v qh[2], ql[2];
    {
        const float* qp = Q + kvbase + (size_t)(q0 + w * 16 + l15) * HD + quad * 8;
        #pragma unroll
        for (int st = 0; st < 2; st++) {
            float4 a = *(const float4*)(qp + st * 32);
            float4 b = *(const float4*)(qp + st * 32 + 4);
            float x[8] = {a.x, a.y, a.z, a.w, b.x, b.y, b.z, b.w};
            #pragma unroll
            for (int e = 0; e < 8; e++) {
                unsigned short h = f32_to_bf16(x[e]);
                qh[st][e] = (short)h;
                ql[st][e] = (short)f32_to_bf16(x[e] - bf16_to_f32(h));
            }
        }
    }

    f4v o[4];
    #pragma unroll
    for (int nt = 0; nt < 4; nt++) o[nt] = (f4v){0.f, 0.f, 0.f, 0.f};
    float mprev[4] = {-1e30f, -1e30f, -1e30f, -1e30f};
    float lrun[4]  = {0.f, 0.f, 0.f, 0.f};

    for (int k0 = 0; k0 < SEQ; k0 += 32) {
        __syncthreads();

        {
            int row = t >> 3;
            int dc  = (t & 7) * 8;
            const float* kp = Kg + kvbase + (size_t)(k0 + row) * HD + dc;
            float4 a = *(const float4*)kp;
            float4 b = *(const float4*)(kp + 4);
            float x[8] = {a.x, a.y, a.z, a.w, b.x, b.y, b.z, b.w};
            unsigned base = row * 72 + dc;
            #pragma unroll
            for (int j = 0; j < 4; j++) {
                unsigned short h0 = f32_to_bf16(x[2 * j]);
                unsigned short h1 = f32_to_bf16(x[2 * j + 1]);
                unsigned short l0 = f32_to_bf16(x[2 * j] - bf16_to_f32(h0));
                unsigned short l1 = f32_to_bf16(x[2 * j + 1] - bf16_to_f32(h1));
                *(unsigned*)&KhS[base + 2 * j] = (unsigned)h0 | ((unsigned)h1 << 16);
                *(unsigned*)&KlS[base + 2 * j] = (unsigned)l0 | ((unsigned)l1 << 16);
            }
        }
        {
            int d  = t & 63;
            int sw = ((d >> 3) & 3) << 3;
            #pragma unroll
            for (int ii = 0; ii < 4; ii++) {
                int kp2 = (t >> 6) + ii * 4;
                float v0 = Vg[kvbase + (size_t)(k0 + 2 * kp2)     * HD + d];
                float v1 = Vg[kvbase + (size_t)(k0 + 2 * kp2 + 1) * HD + d];
                unsigned short h0 = f32_to_bf16(v0);
                unsigned short h1 = f32_to_bf16(v1);
                unsigned short l0 = f32_to_bf16(v0 - bf16_to_f32(h0));
                unsigned short l1 = f32_to_bf16(v1 - bf16_to_f32(h1));
                int col = (2 * kp2) ^ sw;
                *(unsigned*)&VthS[d * 40 + col] = (unsigned)h0 | ((unsigned)h1 << 16);
                *(unsigned*)&VtlS[d * 40 + col] = (unsigned)l0 | ((unsigned)l1 << 16);
            }
        }
        __syncthreads();

        f4v s0 = (f4v){0.f, 0.f, 0.f, 0.f};
        f4v s1 = (f4v){0.f, 0.f, 0.f, 0.f};
        {
            const unsigned short* kb0 = KhS + l15 * 72 + quad * 8;
            const unsigned short* lb0 = KlS + l15 * 72 + quad * 8;
            s8v kh0 = *(const s8v*)kb0, kh1 = *(const s8v*)(kb0 + 32);
            s8v kl0 = *(const s8v*)lb0, kl1 = *(const s8v*)(lb0 + 32);
            s0 = MFMA16(qh[0], kh0, s0); s0 = MFMA16(qh[1], kh1, s0);
            s0 = MFMA16(ql[0], kh0, s0); s0 = MFMA16(ql[1], kh1, s0);
            s0 = MFMA16(qh[0], kl0, s0); s0 = MFMA16(qh[1], kl1, s0);
            const unsigned short* kb1 = KhS + (16 + l15) * 72 + quad * 8;
            const unsigned short* lb1 = KlS + (16 + l15) * 72 + quad * 8;
            s8v kh2 = *(const s8v*)kb1, kh3 = *(const s8v*)(kb1 + 32);
            s8v kl2 = *(const s8v*)lb1, kl3 = *(const s8v*)(lb1 + 32);
            s1 = MFMA16(qh[0], kh2, s1); s1 = MFMA16(qh[1], kh3, s1);
            s1 = MFMA16(ql[0], kh2, s1); s1 = MFMA16(ql[1], kh3, s1);
            s1 = MFMA16(qh[0], kl2, s1); s1 = MFMA16(qh[1], kl3, s1);
        }

        #pragma unroll
        for (int r = 0; r < 4; r++) {
            float sr0 = s0[r] * 0.125f;
            float sr1 = s1[r] * 0.125f;
            float mt = fmaxf(sr0, sr1);
            mt = fmaxf(mt, __shfl_xor(mt, 1, 64));
            mt = fmaxf(mt, __shfl_xor(mt, 2, 64));
            mt = fmaxf(mt, __shfl_xor(mt, 4, 64));
            mt = fmaxf(mt, __shfl_xor(mt, 8, 64));
            float mnew  = fmaxf(mprev[r], mt);
            float alpha = __expf(mprev[r] - mnew);
            mprev[r] = mnew;
            float p0 = __expf(sr0 - mnew);
            float p1 = __expf(sr1 - mnew);
            float rs = p0 + p1;
            rs += __shfl_xor(rs, 1, 64);
            rs += __shfl_xor(rs, 2, 64);
            rs += __shfl_xor(rs, 4, 64);
            rs += __shfl_xor(rs, 8, 64);
            lrun[r] = lrun[r] * alpha + rs;
            o[0][r] *= alpha; o[1][r] *= alpha; o[2][r] *= alpha; o[3][r] *= alpha;

            int row_l = w * 16 + quad * 4 + r;
            int cs = row_l & 8;
            int c0 = l15 ^ cs;
            int c1 = (16 + l15) ^ cs;
            unsigned short h = f32_to_bf16(p0);
            PhS[row_l * 40 + c0] = h;
            PlS[row_l * 40 + c0] = f32_to_bf16(p0 - bf16_to_f32(h));
            h = f32_to_bf16(p1);
            PhS[row_l * 40 + c1] = h;
            PlS[row_l * 40 + c1] = f32_to_bf16(p1 - bf16_to_f32(h));
        }

        {
            const int prow = w * 16 + l15;
            const unsigned short* pb  = PhS + prow * 40 + ((quad * 8) ^ (prow & 8));
            const unsigned short* plb = PlS + prow * 40 + ((quad * 8) ^ (prow & 8));
            s8v ph = *(const s8v*)pb;
            s8v pl = *(const s8v*)plb;
            #pragma unroll
            for (int nt = 0; nt < 4; nt++) {
                int dim = nt * 16 + l15;
                int voff = dim * 40 + ((quad * 8) ^ (((dim >> 3) & 3) << 3));
                s8v vh = *(const s8v*)&VthS[voff];
                s8v vl = *(const s8v*)&VtlS[voff];
                o[nt] = MFMA16(ph, vh, o[nt]);
                o[nt] = MFMA16(ph, vl, o[nt]);
                o[nt] = MFMA16(pl, vh, o[nt]);
            }
        }
    }

    const int b = bh >> 4;
    const int h = bh & 15;
    #pragma unroll
    for (int r = 0; r < 4; r++) {
        float inv_l = 1.0f / lrun[r];
        int s = q0 + w * 16 + quad * 4 + r;
        size_t obase = (((size_t)b * SEQ + s) * NH + h) * HD;
        #pragma unroll
        for (int nt = 0; nt < 4; nt++) {
            float v = o[nt][r] * inv_l;
            unsigned short hv = f32_to_bf16(v);
            AOh[obase + nt * 16 + l15] = hv;
            AOl[obase + nt * 16 + l15] = f32_to_bf16(v - bf16_to_f32(hv));
        }
    }
}

// ---------------------------------------------------------------------------
extern "C" void kernel_launch(void* const* d_in, const int* in_sizes, int n_in,
                              void* d_out, int out_size, void* d_ws, size_t ws_size,
                              hipStream_t stream) {
    const float* x  = (const float*)d_in[0];
    const float* Wq = (const float*)d_in[1];
    const float* bq = (const float*)d_in[2];
    const float* Wk = (const float*)d_in[3];
    const float* bk = (const float*)d_in[4];
    const float* Wv = (const float*)d_in[5];
    const float* bv = (const float*)d_in[6];
    const float* Wo = (const float*)d_in[7];
    const float* bo = (const float*)d_in[8];
    float* out = (float*)d_out;

    const size_t TEN = (size_t)MROWS * KDIM;     // 4,194,304
    const size_t WSZ = (size_t)KDIM * KDIM;      // 1,048,576

    float* Qws = (float*)d_ws;
    float* Kws = Qws + TEN;
    float* Vws = Kws + TEN;
    unsigned short* xh = (unsigned short*)(Vws + TEN);
    unsigned short* xl = xh + TEN;
    unsigned short* Wqh = xl + TEN;
    unsigned short* Wql = Wqh + WSZ;
    unsigned short* Wkh = Wql + WSZ;
    unsigned short* Wkl = Wkh + WSZ;
    unsigned short* Wvh = Wkl + WSZ;
    unsigned short* Wvl = Wvh + WSZ;
    unsigned short* Woh = Wvl + WSZ;
    unsigned short* Wol = Woh + WSZ;
    // x is dead after the QKV GEMMs; reuse its hi/lo buffers for attn output
    unsigned short* AOh = xh;
    unsigned short* AOl = xl;

    convert_hl<<<8192, 256, 0, stream>>>(x, Wq, Wk, Wv, Wo,
                                         xh, xl, Wqh, Wql, Wkh, Wkl,
                                         Wvh, Wvl, Woh, Wol);

    dim3 gGemm(MROWS / 128, KDIM / 128);     // (32, 8)
    gemm_mfma<2><<<gGemm, 256, 0, stream>>>(xh, xl, Wqh, Wql, bq, Qws);
    gemm_mfma<2><<<gGemm, 256, 0, stream>>>(xh, xl, Wkh, Wkl, bk, Kws);
    gemm_mfma<1><<<gGemm, 256, 0, stream>>>(xh, xl, Wvh, Wvl, bv, Vws);

    dim3 gAttn(SEQ / 64, BATCH * NH);        // (32, 32)
    flash_attn<<<gAttn, 256, 0, stream>>>(Qws, Kws, Vws, AOh, AOl);

    gemm_mfma<0><<<gGemm, 256, 0, stream>>>(AOh, AOl, Woh, Wol, bo, out);
}

// Round 4
// 580.873 us; speedup vs baseline: 3.9630x; 1.1550x over previous
//
#include <hip/hip_runtime.h>
#include <math.h>

#define D_MODEL 1024
#define NH 16
#define HD 64
#define SEQ 2048
#define BATCH 2
#define MROWS (BATCH*SEQ)   // 4096
#define KDIM 1024

typedef unsigned short u16;
typedef __attribute__((ext_vector_type(8))) short s8v;   // 8 bf16 (4 VGPRs)
typedef __attribute__((ext_vector_type(4))) float f4v;   // 4 fp32 acc

#define MFMA16(a, b, c) __builtin_amdgcn_mfma_f32_16x16x32_bf16(a, b, c, 0, 0, 0)

__device__ __forceinline__ u16 f32_to_bf16(float f) {
    unsigned u = __float_as_uint(f);
    unsigned r = u + 0x7fffu + ((u >> 16) & 1u);   // RNE
    return (u16)(r >> 16);
}
__device__ __forceinline__ float bf16_to_f32(u16 h) {
    return __uint_as_float(((unsigned)h) << 16);
}

// async global->LDS, 16 B per lane (global_load_lds_dwordx4)
__device__ __forceinline__ void ld16(const u16* g, u16* l) {
    __builtin_amdgcn_global_load_lds(
        (const __attribute__((address_space(1))) void*)g,
        (__attribute__((address_space(3))) void*)l, 16, 0, 0);
}

// ---------------------------------------------------------------------------
// Fused fp32 -> bf16 hi/lo conversion for x (2^20 float4s) + 4 W (2^18 each).
// ---------------------------------------------------------------------------
__global__ __launch_bounds__(256)
void convert_hl(const float* __restrict__ x,
                const float* __restrict__ Wq, const float* __restrict__ Wk,
                const float* __restrict__ Wv, const float* __restrict__ Wo,
                u16* __restrict__ xh, u16* __restrict__ xl,
                u16* __restrict__ Wqh, u16* __restrict__ Wql,
                u16* __restrict__ Wkh, u16* __restrict__ Wkl,
                u16* __restrict__ Wvh, u16* __restrict__ Wvl,
                u16* __restrict__ Woh, u16* __restrict__ Wol) {
    int i = blockIdx.x * 256 + threadIdx.x;
    const float* src;
    u16 *h, *l;
    int idx;
    if (i < (1 << 20)) {
        src = x; h = xh; l = xl; idx = i;
    } else {
        int j = i - (1 << 20);
        int w = j >> 18;
        idx = j & ((1 << 18) - 1);
        switch (w) {
            case 0:  src = Wq; h = Wqh; l = Wql; break;
            case 1:  src = Wk; h = Wkh; l = Wkl; break;
            case 2:  src = Wv; h = Wvh; l = Wvl; break;
            default: src = Wo; h = Woh; l = Wol; break;
        }
    }
    float4 v = ((const float4*)src)[idx];
    ushort4 hv, lv;
    hv.x = f32_to_bf16(v.x); lv.x = f32_to_bf16(v.x - bf16_to_f32(hv.x));
    hv.y = f32_to_bf16(v.y); lv.y = f32_to_bf16(v.y - bf16_to_f32(hv.y));
    hv.z = f32_to_bf16(v.z); lv.z = f32_to_bf16(v.z - bf16_to_f32(hv.z));
    hv.w = f32_to_bf16(v.w); lv.w = f32_to_bf16(v.w - bf16_to_f32(hv.w));
    ((ushort4*)h)[idx] = hv;
    ((ushort4*)l)[idx] = lv;
}

// ---------------------------------------------------------------------------
// Fused QKV split-bf16 MFMA GEMM. Grid (32, 24): y>>3 selects Q/K/V,
// y&7 selects the 128-col n-tile. 128x128 tile, BK=32, 4 waves.
// Q,K epilogue: fused RoPE, writes bf16 hi/lo [B,H,S,D] (natural).
// V epilogue: LDS transpose, writes bf16 hi/lo [B,H,D,S] (key-major).
// ---------------------------------------------------------------------------
__global__ __launch_bounds__(256, 2)
void qkv_gemm(const u16* __restrict__ xh_g, const u16* __restrict__ xl_g,
              const u16* __restrict__ Wqh, const u16* __restrict__ Wql,
              const u16* __restrict__ Wkh, const u16* __restrict__ Wkl,
              const u16* __restrict__ Wvh, const u16* __restrict__ Wvl,
              const float* __restrict__ bq, const float* __restrict__ bk,
              const float* __restrict__ bv,
              u16* __restrict__ Qh, u16* __restrict__ Ql,
              u16* __restrict__ Kh, u16* __restrict__ Kl,
              u16* __restrict__ Vth, u16* __restrict__ Vtl) {
    __shared__ u16 SMEM[16384];     // 32 KB: staging tiles, then V-transpose
    u16* Ah = SMEM;                 // [128][32]
    u16* Al = SMEM + 4096;
    u16* Bh = SMEM + 8192;
    u16* Bl = SMEM + 12288;

    const int t    = threadIdx.x;
    const int w    = t >> 6;
    const int lane = t & 63;
    const int quad = lane >> 4;
    const int l15  = lane & 15;
    const int wr   = w >> 1;
    const int wc   = w & 1;
    const int m0b  = blockIdx.x * 128;
    const int wsel = blockIdx.y >> 3;
    const int n0   = (blockIdx.y & 7) * 128;

    const u16 *Bh_g, *Bl_g;
    const float* bias;
    if (wsel == 0)      { Bh_g = Wqh; Bl_g = Wql; bias = bq; }
    else if (wsel == 1) { Bh_g = Wkh; Bl_g = Wkl; bias = bk; }
    else                { Bh_g = Wvh; Bl_g = Wvl; bias = bv; }

    const int srow = t >> 2;            // 0..63
    const int scol = (t & 3) * 8;
    const u16* agh = xh_g + (size_t)(m0b + srow) * KDIM + scol;
    const u16* agl = xl_g + (size_t)(m0b + srow) * KDIM + scol;
    const u16* bgh = Bh_g + (size_t)(n0 + srow) * KDIM + scol;
    const u16* bgl = Bl_g + (size_t)(n0 + srow) * KDIM + scol;
    const size_t rstep = (size_t)64 * KDIM;

    f4v acc[4][4];
    #pragma unroll
    for (int i = 0; i < 4; i++)
        #pragma unroll
        for (int j = 0; j < 4; j++)
            acc[i][j] = (f4v){0.f, 0.f, 0.f, 0.f};

    for (int k0 = 0; k0 < KDIM; k0 += 32) {
        ld16(agh + k0,         &Ah[t * 8]);
        ld16(agh + rstep + k0, &Ah[(256 + t) * 8]);
        ld16(agl + k0,         &Al[t * 8]);
        ld16(agl + rstep + k0, &Al[(256 + t) * 8]);
        ld16(bgh + k0,         &Bh[t * 8]);
        ld16(bgh + rstep + k0, &Bh[(256 + t) * 8]);
        ld16(bgl + k0,         &Bl[t * 8]);
        ld16(bgl + rstep + k0, &Bl[(256 + t) * 8]);
        __syncthreads();

        s8v ah[4], al[4], bh[4], bl[4];
        #pragma unroll
        for (int i = 0; i < 4; i++) {
            int ar = (wr * 64 + i * 16 + l15) * 32 + quad * 8;
            ah[i] = *(const s8v*)&Ah[ar];
            al[i] = *(const s8v*)&Al[ar];
            int br = (wc * 64 + i * 16 + l15) * 32 + quad * 8;
            bh[i] = *(const s8v*)&Bh[br];
            bl[i] = *(const s8v*)&Bl[br];
        }
        #pragma unroll
        for (int mt = 0; mt < 4; mt++) {
            #pragma unroll
            for (int nt = 0; nt < 4; nt++) {
                acc[mt][nt] = MFMA16(ah[mt], bh[nt], acc[mt][nt]);
                acc[mt][nt] = MFMA16(ah[mt], bl[nt], acc[mt][nt]);
                acc[mt][nt] = MFMA16(al[mt], bh[nt], acc[mt][nt]);
            }
        }
        __syncthreads();
    }

    if (wsel < 2) {
        // ---- Q/K: fused RoPE, write bf16 hi/lo natural [B,H,S,D] ----
        u16* Oh = (wsel == 0) ? Qh : Kh;
        u16* Ol = (wsel == 0) ? Ql : Kl;
        #pragma unroll
        for (int mt = 0; mt < 4; mt++) {
            #pragma unroll
            for (int r = 0; r < 4; r++) {
                int m = m0b + wr * 64 + mt * 16 + quad * 4 + r;
                int b = m >> 11;
                int s = m & 2047;
                #pragma unroll
                for (int nt = 0; nt < 2; nt++) {
                    int n1 = n0 + wc * 64 + nt * 16 + l15;
                    int dd = n1 & 31;
                    float v1 = acc[mt][nt][r]     + bias[n1];
                    float v2 = acc[mt][nt + 2][r] + bias[n1 + 32];
                    float inv = powf(10000.0f, -(float)dd * (1.0f / 32.0f));
                    float ang = (float)s * inv;
                    float c  = cosf(ang);
                    float sn = sinf(ang);
                    float r1 = v1 * c - v2 * sn;
                    float r2 = v2 * c + v1 * sn;
                    int h = n1 >> 6;
                    int d = n1 & 63;
                    size_t base = (((size_t)b * NH + h) * SEQ + s) << 6;
                    u16 h1 = f32_to_bf16(r1);
                    u16 h2 = f32_to_bf16(r2);
                    Oh[base + d]      = h1;
                    Oh[base + d + 32] = h2;
                    Ol[base + d]      = f32_to_bf16(r1 - bf16_to_f32(h1));
                    Ol[base + d + 32] = f32_to_bf16(r2 - bf16_to_f32(h2));
                }
            }
        }
    } else {
        // ---- V: transpose via LDS (hi pass, then lo pass) ----
        const int b  = m0b >> 11;
        const int s0 = m0b & 2047;
        const int h0 = (blockIdx.y & 7) * 2;
        #pragma unroll
        for (int pass = 0; pass < 2; pass++) {
            __syncthreads();
            #pragma unroll
            for (int mt = 0; mt < 4; mt++) {
                #pragma unroll
                for (int nt = 0; nt < 4; nt++) {
                    int n = wc * 64 + nt * 16 + l15;
                    float bv_ = bias[n0 + n];
                    #pragma unroll
                    for (int r = 0; r < 4; r++) {
                        int m = wr * 64 + mt * 16 + quad * 4 + r;
                        float v = acc[mt][nt][r] + bv_;
                        u16 hv = f32_to_bf16(v);
                        u16 st = pass ? f32_to_bf16(v - bf16_to_f32(hv)) : hv;
                        SMEM[n * 128 + ((((m >> 3) ^ (n & 15))) << 3) + (m & 7)] = st;
                    }
                }
            }
            __syncthreads();
            u16* dst = pass ? Vtl : Vth;
            int n = t >> 1;
            int half = t & 1;
            int d  = n & 63;
            int hh = n >> 6;
            size_t obase = ((size_t)((b * NH + h0 + hh) * HD + d)) * SEQ + s0;
            #pragma unroll
            for (int c = 0; c < 8; c++) {
                int mc = half * 8 + c;
                s8v val = *(const s8v*)&SMEM[n * 128 + ((mc ^ (n & 15)) << 3)];
                *(s8v*)(dst + obase + mc * 8) = val;
            }
        }
    }
}

// ---------------------------------------------------------------------------
// Global max of per-row K norm^2 (rows = B*NH*SEQ, 64 dims). 4 threads/row.
// ---------------------------------------------------------------------------
__global__ __launch_bounds__(256)
void kmax_kernel(const u16* __restrict__ Kh, const u16* __restrict__ Kl,
                 float* __restrict__ kmax2) {
    int gid = blockIdx.x * 256 + threadIdx.x;
    int row = gid >> 2, part = gid & 3;
    size_t base = (size_t)row * 64 + part * 16;
    s8v h0 = *(const s8v*)(Kh + base);
    s8v h1 = *(const s8v*)(Kh + base + 8);
    s8v l0 = *(const s8v*)(Kl + base);
    s8v l1 = *(const s8v*)(Kl + base + 8);
    float sum = 0.f;
    #pragma unroll
    for (int e = 0; e < 8; e++) {
        float a = bf16_to_f32((u16)h0[e]) + bf16_to_f32((u16)l0[e]);
        float b = bf16_to_f32((u16)h1[e]) + bf16_to_f32((u16)l1[e]);
        sum += a * a + b * b;
    }
    sum += __shfl_xor(sum, 1, 64);
    sum += __shfl_xor(sum, 2, 64);   // full row norm^2 (replicated in 4 lanes)
    sum = fmaxf(sum, __shfl_xor(sum, 4, 64));
    sum = fmaxf(sum, __shfl_xor(sum, 8, 64));
    sum = fmaxf(sum, __shfl_xor(sum, 16, 64));
    sum = fmaxf(sum, __shfl_xor(sum, 32, 64));
    __shared__ float red[4];
    if ((threadIdx.x & 63) == 0) red[threadIdx.x >> 6] = sum;
    __syncthreads();
    if (threadIdx.x == 0) {
        float m = fmaxf(fmaxf(red[0], red[1]), fmaxf(red[2], red[3]));
        atomicMax((int*)kmax2, __float_as_int(m));
    }
}

// ---------------------------------------------------------------------------
// MFMA flash attention, split-bf16, STATIC-bound softmax (no online rescale).
// Q,K natural bf16 hi/lo [B,H,S,D]; V transposed bf16 hi/lo [B,H,D,S].
// m0 = |q_row| * max|k| / 8 >= every logit  =>  exp never overflows; bf16's
// fp32 exponent range makes small p exact. l accumulated per-lane, reduced once.
// ---------------------------------------------------------------------------
__global__ __launch_bounds__(256)
void flash_attn(const u16* __restrict__ Qh, const u16* __restrict__ Ql,
                const u16* __restrict__ Kh, const u16* __restrict__ Kl,
                const u16* __restrict__ Vth, const u16* __restrict__ Vtl,
                const float* __restrict__ kmax2,
                u16* __restrict__ AOh, u16* __restrict__ AOl) {
    __shared__ __align__(16) u16 KhS[32 * 72];
    __shared__ __align__(16) u16 KlS[32 * 72];
    __shared__ __align__(16) u16 VthS[64 * 40];
    __shared__ __align__(16) u16 VtlS[64 * 40];
    __shared__ __align__(16) u16 PhS[64 * 40];
    __shared__ __align__(16) u16 PlS[64 * 40];

    const int t    = threadIdx.x;
    const int w    = t >> 6;
    const int lane = t & 63;
    const int quad = lane >> 4;
    const int l15  = lane & 15;

    const int q0 = blockIdx.x * 64;
    const int bh = blockIdx.y;
    const size_t kvbase = (size_t)bh * SEQ * HD;

    // ---- Q fragments straight from bf16 hi/lo ----
    s8v qh[2], ql[2];
    {
        size_t qb = kvbase + (size_t)(q0 + w * 16 + l15) * HD + quad * 8;
        qh[0] = *(const s8v*)(Qh + qb);
        qh[1] = *(const s8v*)(Qh + qb + 32);
        ql[0] = *(const s8v*)(Ql + qb);
        ql[1] = *(const s8v*)(Ql + qb + 32);
    }
    // row norm^2 of q (A-frag row = l15; partials spread over quad lanes)
    float qn2 = 0.f;
    #pragma unroll
    for (int st = 0; st < 2; st++)
        #pragma unroll
        for (int e = 0; e < 8; e++) {
            float v = bf16_to_f32((u16)qh[st][e]) + bf16_to_f32((u16)ql[st][e]);
            qn2 += v * v;
        }
    qn2 += __shfl_xor(qn2, 16, 64);
    qn2 += __shfl_xor(qn2, 32, 64);
    float km2 = kmax2[0];
    float m0[4];
    #pragma unroll
    for (int r = 0; r < 4; r++) {
        int src = (lane & 48) | (quad * 4 + r);
        float qr = __shfl(qn2, src, 64);
        m0[r] = sqrtf(qr * km2) * 0.125f;
    }

    f4v o[4];
    #pragma unroll
    for (int nt = 0; nt < 4; nt++) o[nt] = (f4v){0.f, 0.f, 0.f, 0.f};
    float lsum[4] = {0.f, 0.f, 0.f, 0.f};

    for (int k0 = 0; k0 < SEQ; k0 += 32) {
        __syncthreads();

        // ---- stage K tile (pure copy) ----
        {
            int row = t >> 3;
            int dc  = (t & 7) * 8;
            size_t g = kvbase + (size_t)(k0 + row) * HD + dc;
            *(s8v*)&KhS[row * 72 + dc] = *(const s8v*)(Kh + g);
            *(s8v*)&KlS[row * 72 + dc] = *(const s8v*)(Kl + g);
        }
        // ---- stage V tile (pure copy, already transposed in global) ----
        {
            int d  = t >> 2;
            int kc = (t & 3) * 8;
            size_t g = (size_t)bh * HD * SEQ + (size_t)d * SEQ + k0 + kc;
            int col = kc ^ (((d >> 3) & 3) << 3);
            *(s8v*)&VthS[d * 40 + col] = *(const s8v*)(Vth + g);
            *(s8v*)&VtlS[d * 40 + col] = *(const s8v*)(Vtl + g);
        }
        __syncthreads();

        // ---- QK^T: 16 q-rows x 32 keys per wave, split-bf16 ----
        f4v s0 = (f4v){0.f, 0.f, 0.f, 0.f};
        f4v s1 = (f4v){0.f, 0.f, 0.f, 0.f};
        {
            const u16* kb0 = KhS + l15 * 72 + quad * 8;
            const u16* lb0 = KlS + l15 * 72 + quad * 8;
            s8v kh0 = *(const s8v*)kb0, kh1 = *(const s8v*)(kb0 + 32);
            s8v kl0 = *(const s8v*)lb0, kl1 = *(const s8v*)(lb0 + 32);
            s0 = MFMA16(qh[0], kh0, s0); s0 = MFMA16(qh[1], kh1, s0);
            s0 = MFMA16(ql[0], kh0, s0); s0 = MFMA16(ql[1], kh1, s0);
            s0 = MFMA16(qh[0], kl0, s0); s0 = MFMA16(qh[1], kl1, s0);
            const u16* kb1 = KhS + (16 + l15) * 72 + quad * 8;
            const u16* lb1 = KlS + (16 + l15) * 72 + quad * 8;
            s8v kh2 = *(const s8v*)kb1, kh3 = *(const s8v*)(kb1 + 32);
            s8v kl2 = *(const s8v*)lb1, kl3 = *(const s8v*)(lb1 + 32);
            s1 = MFMA16(qh[0], kh2, s1); s1 = MFMA16(qh[1], kh3, s1);
            s1 = MFMA16(ql[0], kh2, s1); s1 = MFMA16(ql[1], kh3, s1);
            s1 = MFMA16(qh[0], kl2, s1); s1 = MFMA16(qh[1], kl3, s1);
        }

        // ---- static softmax: p = exp(s/8 - m0); accumulate l per-lane ----
        #pragma unroll
        for (int r = 0; r < 4; r++) {
            float p0 = __expf(s0[r] * 0.125f - m0[r]);
            float p1 = __expf(s1[r] * 0.125f - m0[r]);
            lsum[r] += p0 + p1;

            int row_l = w * 16 + quad * 4 + r;
            int cs = row_l & 8;
            int c0 = l15 ^ cs;
            int c1 = (16 + l15) ^ cs;
            u16 h = f32_to_bf16(p0);
            PhS[row_l * 40 + c0] = h;
            PlS[row_l * 40 + c0] = f32_to_bf16(p0 - bf16_to_f32(h));
            h = f32_to_bf16(p1);
            PhS[row_l * 40 + c1] = h;
            PlS[row_l * 40 + c1] = f32_to_bf16(p1 - bf16_to_f32(h));
        }

        // ---- PV: split-bf16, no rescale needed ----
        {
            const int prow = w * 16 + l15;
            const u16* pb  = PhS + prow * 40 + ((quad * 8) ^ (prow & 8));
            const u16* plb = PlS + prow * 40 + ((quad * 8) ^ (prow & 8));
            s8v ph = *(const s8v*)pb;
            s8v pl = *(const s8v*)plb;
            #pragma unroll
            for (int nt = 0; nt < 4; nt++) {
                int dim = nt * 16 + l15;
                int voff = dim * 40 + ((quad * 8) ^ (((dim >> 3) & 3) << 3));
                s8v vh = *(const s8v*)&VthS[voff];
                s8v vl = *(const s8v*)&VtlS[voff];
                o[nt] = MFMA16(ph, vh, o[nt]);
                o[nt] = MFMA16(ph, vl, o[nt]);
                o[nt] = MFMA16(pl, vh, o[nt]);
            }
        }
    }

    // ---- epilogue: reduce l across the 16 key-lanes, normalize, write ----
    const int b = bh >> 4;
    const int h = bh & 15;
    #pragma unroll
    for (int r = 0; r < 4; r++) {
        float l = lsum[r];
        l += __shfl_xor(l, 1, 64);
        l += __shfl_xor(l, 2, 64);
        l += __shfl_xor(l, 4, 64);
        l += __shfl_xor(l, 8, 64);
        float inv_l = 1.0f / l;
        int s = q0 + w * 16 + quad * 4 + r;
        size_t obase = (((size_t)b * SEQ + s) * NH + h) * HD;
        #pragma unroll
        for (int nt = 0; nt < 4; nt++) {
            float v = o[nt][r] * inv_l;
            u16 hv = f32_to_bf16(v);
            AOh[obase + nt * 16 + l15] = hv;
            AOl[obase + nt * 16 + l15] = f32_to_bf16(v - bf16_to_f32(hv));
        }
    }
}

// ---------------------------------------------------------------------------
// Out-projection: split-bf16 MFMA GEMM, fp32 output [m*1024 + n].
// ---------------------------------------------------------------------------
__global__ __launch_bounds__(256, 2)
void gemm_out(const u16* __restrict__ Ah_g, const u16* __restrict__ Al_g,
              const u16* __restrict__ Bh_g, const u16* __restrict__ Bl_g,
              const float* __restrict__ bias, float* __restrict__ out) {
    __shared__ u16 Ah[128 * 32];
    __shared__ u16 Al[128 * 32];
    __shared__ u16 Bh[128 * 32];
    __shared__ u16 Bl[128 * 32];

    const int t    = threadIdx.x;
    const int w    = t >> 6;
    const int lane = t & 63;
    const int quad = lane >> 4;
    const int l15  = lane & 15;
    const int wr   = w >> 1;
    const int wc   = w & 1;
    const int m0   = blockIdx.x * 128;
    const int n0   = blockIdx.y * 128;

    const int srow = t >> 2;
    const int scol = (t & 3) * 8;
    const u16* agh = Ah_g + (size_t)(m0 + srow) * KDIM + scol;
    const u16* agl = Al_g + (size_t)(m0 + srow) * KDIM + scol;
    const u16* bgh = Bh_g + (size_t)(n0 + srow) * KDIM + scol;
    const u16* bgl = Bl_g + (size_t)(n0 + srow) * KDIM + scol;
    const size_t rstep = (size_t)64 * KDIM;

    f4v acc[4][4];
    #pragma unroll
    for (int i = 0; i < 4; i++)
        #pragma unroll
        for (int j = 0; j < 4; j++)
            acc[i][j] = (f4v){0.f, 0.f, 0.f, 0.f};

    for (int k0 = 0; k0 < KDIM; k0 += 32) {
        ld16(agh + k0,         &Ah[t * 8]);
        ld16(agh + rstep + k0, &Ah[(256 + t) * 8]);
        ld16(agl + k0,         &Al[t * 8]);
        ld16(agl + rstep + k0, &Al[(256 + t) * 8]);
        ld16(bgh + k0,         &Bh[t * 8]);
        ld16(bgh + rstep + k0, &Bh[(256 + t) * 8]);
        ld16(bgl + k0,         &Bl[t * 8]);
        ld16(bgl + rstep + k0, &Bl[(256 + t) * 8]);
        __syncthreads();

        s8v ah[4], al[4], bh[4], bl[4];
        #pragma unroll
        for (int i = 0; i < 4; i++) {
            int ar = (wr * 64 + i * 16 + l15) * 32 + quad * 8;
            ah[i] = *(const s8v*)&Ah[ar];
            al[i] = *(const s8v*)&Al[ar];
            int br = (wc * 64 + i * 16 + l15) * 32 + quad * 8;
            bh[i] = *(const s8v*)&Bh[br];
            bl[i] = *(const s8v*)&Bl[br];
        }
        #pragma unroll
        for (int mt = 0; mt < 4; mt++) {
            #pragma unroll
            for (int nt = 0; nt < 4; nt++) {
                acc[mt][nt] = MFMA16(ah[mt], bh[nt], acc[mt][nt]);
                acc[mt][nt] = MFMA16(ah[mt], bl[nt], acc[mt][nt]);
                acc[mt][nt] = MFMA16(al[mt], bh[nt], acc[mt][nt]);
            }
        }
        __syncthreads();
    }

    #pragma unroll
    for (int mt = 0; mt < 4; mt++) {
        #pragma unroll
        for (int nt = 0; nt < 4; nt++) {
            int n = n0 + wc * 64 + nt * 16 + l15;
            float bv = bias[n];
            #pragma unroll
            for (int r = 0; r < 4; r++) {
                int m = m0 + wr * 64 + mt * 16 + quad * 4 + r;
                out[(size_t)m * 1024 + n] = acc[mt][nt][r] + bv;
            }
        }
    }
}

// ---------------------------------------------------------------------------
extern "C" void kernel_launch(void* const* d_in, const int* in_sizes, int n_in,
                              void* d_out, int out_size, void* d_ws, size_t ws_size,
                              hipStream_t stream) {
    const float* x  = (const float*)d_in[0];
    const float* Wq = (const float*)d_in[1];
    const float* bq = (const float*)d_in[2];
    const float* Wk = (const float*)d_in[3];
    const float* bk = (const float*)d_in[4];
    const float* Wv = (const float*)d_in[5];
    const float* bv = (const float*)d_in[6];
    const float* Wo = (const float*)d_in[7];
    const float* bo = (const float*)d_in[8];
    float* out = (float*)d_out;

    const size_t TEN = (size_t)MROWS * KDIM;     // 4,194,304
    const size_t WSZ = (size_t)KDIM * KDIM;      // 1,048,576

    u16* xh  = (u16*)d_ws;
    u16* xl  = xh + TEN;
    u16* Wqh = xl + TEN;
    u16* Wql = Wqh + WSZ;
    u16* Wkh = Wql + WSZ;
    u16* Wkl = Wkh + WSZ;
    u16* Wvh = Wkl + WSZ;
    u16* Wvl = Wvh + WSZ;
    u16* Woh = Wvl + WSZ;
    u16* Wol = Woh + WSZ;
    u16* Qh  = Wol + WSZ;
    u16* Ql  = Qh + TEN;
    u16* Kh  = Ql + TEN;
    u16* Kl  = Kh + TEN;
    u16* Vth = Kl + TEN;
    u16* Vtl = Vth + TEN;
    // dead-buffer reuse: AO <- x hi/lo; kmax scalar <- Wvh (dead after qkv_gemm)
    u16* AOh = xh;
    u16* AOl = xl;
    float* km2 = (float*)Wvh;

    convert_hl<<<8192, 256, 0, stream>>>(x, Wq, Wk, Wv, Wo,
                                         xh, xl, Wqh, Wql, Wkh, Wkl,
                                         Wvh, Wvl, Woh, Wol);

    qkv_gemm<<<dim3(32, 24), 256, 0, stream>>>(xh, xl, Wqh, Wql, Wkh, Wkl,
                                               Wvh, Wvl, bq, bk, bv,
                                               Qh, Ql, Kh, Kl, Vth, Vtl);

    hipMemsetAsync(km2, 0, 4, stream);
    kmax_kernel<<<1024, 256, 0, stream>>>(Kh, Kl, km2);

    flash_attn<<<dim3(SEQ / 64, BATCH * NH), 256, 0, stream>>>(
        Qh, Ql, Kh, Kl, Vth, Vtl, km2, AOh, AOl);

    gemm_out<<<dim3(MROWS / 128, KDIM / 128), 256, 0, stream>>>(
        AOh, AOl, Woh, Wol, bo, out);
}

// Round 5
// 574.625 us; speedup vs baseline: 4.0061x; 1.0109x over previous
//
#include <hip/hip_runtime.h>
#include <math.h>

#define D_MODEL 1024
#define NH 16
#define HD 64
#define SEQ 2048
#define BATCH 2
#define MROWS (BATCH*SEQ)   // 4096
#define KDIM 1024

typedef unsigned short u16;
typedef unsigned int u32;
typedef __attribute__((ext_vector_type(8))) short s8v;   // 8 bf16 (4 VGPRs)
typedef __attribute__((ext_vector_type(4))) float f4v;   // 4 fp32 acc

#define MFMA16(a, b, c) __builtin_amdgcn_mfma_f32_16x16x32_bf16(a, b, c, 0, 0, 0)

__device__ __forceinline__ u16 f32_to_bf16(float f) {
    unsigned u = __float_as_uint(f);
    unsigned r = u + 0x7fffu + ((u >> 16) & 1u);   // RNE
    return (u16)(r >> 16);
}
__device__ __forceinline__ float bf16_to_f32(u16 h) {
    return __uint_as_float(((unsigned)h) << 16);
}
// pack fp32 -> (bf16 hi | bf16 lo<<16) in one u32
__device__ __forceinline__ u32 pack_hl(float f) {
    u32 h = f32_to_bf16(f);
    u32 l = f32_to_bf16(f - bf16_to_f32((u16)h));
    return h | (l << 16);
}
// unpack two packed elems -> hi-pair u32, lo-pair u32
__device__ __forceinline__ void unpack2(u32 p0, u32 p1, u32& hi, u32& lo) {
    hi = __builtin_amdgcn_perm(p1, p0, 0x05040100u);
    lo = __builtin_amdgcn_perm(p1, p0, 0x07060302u);
}

// async global->LDS, 16 B per lane (global_load_lds_dwordx4)
__device__ __forceinline__ void ld16(const void* g, void* l) {
    __builtin_amdgcn_global_load_lds(
        (const __attribute__((address_space(1))) void*)g,
        (__attribute__((address_space(3))) void*)l, 16, 0, 0);
}

// ---------------------------------------------------------------------------
// fp32 -> bf16 hi/lo SoA conversion for x + 4 weights (GEMM operands).
// ---------------------------------------------------------------------------
__global__ __launch_bounds__(256)
void convert_hl(const float* __restrict__ x,
                const float* __restrict__ Wq, const float* __restrict__ Wk,
                const float* __restrict__ Wv, const float* __restrict__ Wo,
                u16* __restrict__ xh, u16* __restrict__ xl,
                u16* __restrict__ Wqh, u16* __restrict__ Wql,
                u16* __restrict__ Wkh, u16* __restrict__ Wkl,
                u16* __restrict__ Wvh, u16* __restrict__ Wvl,
                u16* __restrict__ Woh, u16* __restrict__ Wol) {
    int i = blockIdx.x * 256 + threadIdx.x;
    const float* src;
    u16 *h, *l;
    int idx;
    if (i < (1 << 20)) {
        src = x; h = xh; l = xl; idx = i;
    } else {
        int j = i - (1 << 20);
        int w = j >> 18;
        idx = j & ((1 << 18) - 1);
        switch (w) {
            case 0:  src = Wq; h = Wqh; l = Wql; break;
            case 1:  src = Wk; h = Wkh; l = Wkl; break;
            case 2:  src = Wv; h = Wvh; l = Wvl; break;
            default: src = Wo; h = Woh; l = Wol; break;
        }
    }
    float4 v = ((const float4*)src)[idx];
    ushort4 hv, lv;
    hv.x = f32_to_bf16(v.x); lv.x = f32_to_bf16(v.x - bf16_to_f32(hv.x));
    hv.y = f32_to_bf16(v.y); lv.y = f32_to_bf16(v.y - bf16_to_f32(hv.y));
    hv.z = f32_to_bf16(v.z); lv.z = f32_to_bf16(v.z - bf16_to_f32(hv.z));
    hv.w = f32_to_bf16(v.w); lv.w = f32_to_bf16(v.w - bf16_to_f32(hv.w));
    ((ushort4*)h)[idx] = hv;
    ((ushort4*)l)[idx] = lv;
}

// ---------------------------------------------------------------------------
// Fused QKV split-bf16 MFMA GEMM. Grid (32, 24): y>>3 selects Q/K/V.
// Q,K: fused RoPE, writes PACKED u32 (hi|lo) [B,H,S,D] — full-sector stores.
// V: LDS transpose, bf16 hi/lo SoA [B,H,D,S] (16-B contiguous stores).
// ---------------------------------------------------------------------------
__global__ __launch_bounds__(256, 2)
void qkv_gemm(const u16* __restrict__ xh_g, const u16* __restrict__ xl_g,
              const u16* __restrict__ Wqh, const u16* __restrict__ Wql,
              const u16* __restrict__ Wkh, const u16* __restrict__ Wkl,
              const u16* __restrict__ Wvh, const u16* __restrict__ Wvl,
              const float* __restrict__ bq, const float* __restrict__ bk,
              const float* __restrict__ bv,
              u32* __restrict__ Qp, u32* __restrict__ Kp,
              u16* __restrict__ Vth, u16* __restrict__ Vtl) {
    __shared__ u16 SMEM[16384];     // 32 KB: staging tiles, then V-transpose
    u16* Ah = SMEM;                 // [128][32]
    u16* Al = SMEM + 4096;
    u16* Bh = SMEM + 8192;
    u16* Bl = SMEM + 12288;

    const int t    = threadIdx.x;
    const int w    = t >> 6;
    const int lane = t & 63;
    const int quad = lane >> 4;
    const int l15  = lane & 15;
    const int wr   = w >> 1;
    const int wc   = w & 1;
    const int m0b  = blockIdx.x * 128;
    const int wsel = blockIdx.y >> 3;
    const int n0   = (blockIdx.y & 7) * 128;

    const u16 *Bh_g, *Bl_g;
    const float* bias;
    if (wsel == 0)      { Bh_g = Wqh; Bl_g = Wql; bias = bq; }
    else if (wsel == 1) { Bh_g = Wkh; Bl_g = Wkl; bias = bk; }
    else                { Bh_g = Wvh; Bl_g = Wvl; bias = bv; }

    const int srow = t >> 2;            // 0..63
    const int scol = (t & 3) * 8;
    const u16* agh = xh_g + (size_t)(m0b + srow) * KDIM + scol;
    const u16* agl = xl_g + (size_t)(m0b + srow) * KDIM + scol;
    const u16* bgh = Bh_g + (size_t)(n0 + srow) * KDIM + scol;
    const u16* bgl = Bl_g + (size_t)(n0 + srow) * KDIM + scol;
    const size_t rstep = (size_t)64 * KDIM;

    f4v acc[4][4];
    #pragma unroll
    for (int i = 0; i < 4; i++)
        #pragma unroll
        for (int j = 0; j < 4; j++)
            acc[i][j] = (f4v){0.f, 0.f, 0.f, 0.f};

    for (int k0 = 0; k0 < KDIM; k0 += 32) {
        ld16(agh + k0,         &Ah[t * 8]);
        ld16(agh + rstep + k0, &Ah[(256 + t) * 8]);
        ld16(agl + k0,         &Al[t * 8]);
        ld16(agl + rstep + k0, &Al[(256 + t) * 8]);
        ld16(bgh + k0,         &Bh[t * 8]);
        ld16(bgh + rstep + k0, &Bh[(256 + t) * 8]);
        ld16(bgl + k0,         &Bl[t * 8]);
        ld16(bgl + rstep + k0, &Bl[(256 + t) * 8]);
        __syncthreads();

        s8v ah[4], al[4], bh[4], bl[4];
        #pragma unroll
        for (int i = 0; i < 4; i++) {
            int ar = (wr * 64 + i * 16 + l15) * 32 + quad * 8;
            ah[i] = *(const s8v*)&Ah[ar];
            al[i] = *(const s8v*)&Al[ar];
            int br = (wc * 64 + i * 16 + l15) * 32 + quad * 8;
            bh[i] = *(const s8v*)&Bh[br];
            bl[i] = *(const s8v*)&Bl[br];
        }
        #pragma unroll
        for (int mt = 0; mt < 4; mt++) {
            #pragma unroll
            for (int nt = 0; nt < 4; nt++) {
                acc[mt][nt] = MFMA16(ah[mt], bh[nt], acc[mt][nt]);
                acc[mt][nt] = MFMA16(ah[mt], bl[nt], acc[mt][nt]);
                acc[mt][nt] = MFMA16(al[mt], bh[nt], acc[mt][nt]);
            }
        }
        __syncthreads();
    }

    if (wsel < 2) {
        // ---- Q/K: fused RoPE, packed u32 stores (full sectors) ----
        u32* Op = (wsel == 0) ? Qp : Kp;
        #pragma unroll
        for (int mt = 0; mt < 4; mt++) {
            #pragma unroll
            for (int r = 0; r < 4; r++) {
                int m = m0b + wr * 64 + mt * 16 + quad * 4 + r;
                int b = m >> 11;
                int s = m & 2047;
                #pragma unroll
                for (int nt = 0; nt < 2; nt++) {
                    int n1 = n0 + wc * 64 + nt * 16 + l15;
                    int dd = n1 & 31;
                    float v1 = acc[mt][nt][r]     + bias[n1];
                    float v2 = acc[mt][nt + 2][r] + bias[n1 + 32];
                    float inv = powf(10000.0f, -(float)dd * (1.0f / 32.0f));
                    float ang = (float)s * inv;
                    float c  = cosf(ang);
                    float sn = sinf(ang);
                    float r1 = v1 * c - v2 * sn;
                    float r2 = v2 * c + v1 * sn;
                    int h = n1 >> 6;
                    int d = n1 & 63;
                    size_t base = (((size_t)b * NH + h) * SEQ + s) << 6;
                    Op[base + d]      = pack_hl(r1);
                    Op[base + d + 32] = pack_hl(r2);
                }
            }
        }
    } else {
        // ---- V: transpose via LDS (hi pass, then lo pass), 16-B stores ----
        const int b  = m0b >> 11;
        const int s0 = m0b & 2047;
        const int h0 = (blockIdx.y & 7) * 2;
        #pragma unroll
        for (int pass = 0; pass < 2; pass++) {
            __syncthreads();
            #pragma unroll
            for (int mt = 0; mt < 4; mt++) {
                #pragma unroll
                for (int nt = 0; nt < 4; nt++) {
                    int n = wc * 64 + nt * 16 + l15;
                    float bv_ = bias[n0 + n];
                    #pragma unroll
                    for (int r = 0; r < 4; r++) {
                        int m = wr * 64 + mt * 16 + quad * 4 + r;
                        float v = acc[mt][nt][r] + bv_;
                        u16 hv = f32_to_bf16(v);
                        u16 st = pass ? f32_to_bf16(v - bf16_to_f32(hv)) : hv;
                        SMEM[n * 128 + ((((m >> 3) ^ (n & 15))) << 3) + (m & 7)] = st;
                    }
                }
            }
            __syncthreads();
            u16* dst = pass ? Vtl : Vth;
            int n = t >> 1;
            int half = t & 1;
            int d  = n & 63;
            int hh = n >> 6;
            size_t obase = ((size_t)((b * NH + h0 + hh) * HD + d)) * SEQ + s0;
            #pragma unroll
            for (int c = 0; c < 8; c++) {
                int mc = half * 8 + c;
                s8v val = *(const s8v*)&SMEM[n * 128 + ((mc ^ (n & 15)) << 3)];
                *(s8v*)(dst + obase + mc * 8) = val;
            }
        }
    }
}

// ---------------------------------------------------------------------------
// Global max of per-row K norm^2 (rows = B*NH*SEQ, 64 dims). 4 threads/row.
// ---------------------------------------------------------------------------
__global__ __launch_bounds__(256)
void kmax_kernel(const u32* __restrict__ Kp, float* __restrict__ kmax2) {
    int gid = blockIdx.x * 256 + threadIdx.x;
    int row = gid >> 2, part = gid & 3;
    const u32* kp = Kp + (size_t)row * 64 + part * 16;
    float sum = 0.f;
    #pragma unroll
    for (int c = 0; c < 4; c++) {
        uint4 q = *(const uint4*)(kp + c * 4);
        u32 ws[4] = {q.x, q.y, q.z, q.w};
        #pragma unroll
        for (int e = 0; e < 4; e++) {
            float hi = __uint_as_float(ws[e] << 16);
            float lo = __uint_as_float(ws[e] & 0xFFFF0000u);
            float v = hi + lo;
            sum += v * v;
        }
    }
    sum += __shfl_xor(sum, 1, 64);
    sum += __shfl_xor(sum, 2, 64);   // full row norm^2 (replicated in 4 lanes)
    sum = fmaxf(sum, __shfl_xor(sum, 4, 64));
    sum = fmaxf(sum, __shfl_xor(sum, 8, 64));
    sum = fmaxf(sum, __shfl_xor(sum, 16, 64));
    sum = fmaxf(sum, __shfl_xor(sum, 32, 64));
    __shared__ float red[4];
    if ((threadIdx.x & 63) == 0) red[threadIdx.x >> 6] = sum;
    __syncthreads();
    if (threadIdx.x == 0) {
        float m = fmaxf(fmaxf(red[0], red[1]), fmaxf(red[2], red[3]));
        atomicMax((int*)kmax2, __float_as_int(m));
    }
}

// ---------------------------------------------------------------------------
// MFMA flash attention, split-bf16, static-bound softmax.
// Q,K packed u32 [B,H,S,D]; V SoA hi/lo [B,H,D,S]. AO out packed u32 [B,S,H,D].
// ---------------------------------------------------------------------------
__global__ __launch_bounds__(256)
void flash_attn(const u32* __restrict__ Qp, const u32* __restrict__ Kp,
                const u16* __restrict__ Vth, const u16* __restrict__ Vtl,
                const float* __restrict__ kmax2,
                u32* __restrict__ AOp) {
    __shared__ __align__(16) u16 KhS[32 * 72];
    __shared__ __align__(16) u16 KlS[32 * 72];
    __shared__ __align__(16) u16 VthS[64 * 40];
    __shared__ __align__(16) u16 VtlS[64 * 40];
    __shared__ __align__(16) u16 PhS[64 * 40];
    __shared__ __align__(16) u16 PlS[64 * 40];

    const int t    = threadIdx.x;
    const int w    = t >> 6;
    const int lane = t & 63;
    const int quad = lane >> 4;
    const int l15  = lane & 15;

    const int q0 = blockIdx.x * 64;
    const int bh = blockIdx.y;
    const size_t kvbase = (size_t)bh * SEQ * HD;

    union U4 { uint4 q; u32 u[4]; };
    union U8 { u32 u[4]; s8v v; };

    // ---- Q fragments: load packed, unpack to hi/lo ----
    s8v qh[2], ql[2];
    {
        const u32* qp = Qp + kvbase + (size_t)(q0 + w * 16 + l15) * HD + quad * 8;
        #pragma unroll
        for (int st = 0; st < 2; st++) {
            U4 a, b; U8 hi, lo;
            a.q = *(const uint4*)(qp + st * 32);
            b.q = *(const uint4*)(qp + st * 32 + 4);
            unpack2(a.u[0], a.u[1], hi.u[0], lo.u[0]);
            unpack2(a.u[2], a.u[3], hi.u[1], lo.u[1]);
            unpack2(b.u[0], b.u[1], hi.u[2], lo.u[2]);
            unpack2(b.u[2], b.u[3], hi.u[3], lo.u[3]);
            qh[st] = hi.v;
            ql[st] = lo.v;
        }
    }
    // row norm^2 of q
    float qn2 = 0.f;
    #pragma unroll
    for (int st = 0; st < 2; st++)
        #pragma unroll
        for (int e = 0; e < 8; e++) {
            float v = bf16_to_f32((u16)qh[st][e]) + bf16_to_f32((u16)ql[st][e]);
            qn2 += v * v;
        }
    qn2 += __shfl_xor(qn2, 16, 64);
    qn2 += __shfl_xor(qn2, 32, 64);
    float km2 = kmax2[0];
    float m0[4];
    #pragma unroll
    for (int r = 0; r < 4; r++) {
        int src = (lane & 48) | (quad * 4 + r);
        float qr = __shfl(qn2, src, 64);
        m0[r] = sqrtf(qr * km2) * 0.125f;
    }

    f4v o[4];
    #pragma unroll
    for (int nt = 0; nt < 4; nt++) o[nt] = (f4v){0.f, 0.f, 0.f, 0.f};
    float lsum[4] = {0.f, 0.f, 0.f, 0.f};

    for (int k0 = 0; k0 < SEQ; k0 += 32) {
        __syncthreads();

        // ---- stage K tile: load packed u32, unpack to hi/lo LDS rows ----
        {
            int row = t >> 3;
            int dc  = (t & 7) * 8;
            const u32* kp = Kp + kvbase + (size_t)(k0 + row) * HD + dc;
            U4 a, b; U8 hi, lo;
            a.q = *(const uint4*)kp;
            b.q = *(const uint4*)(kp + 4);
            unpack2(a.u[0], a.u[1], hi.u[0], lo.u[0]);
            unpack2(a.u[2], a.u[3], hi.u[1], lo.u[1]);
            unpack2(b.u[0], b.u[1], hi.u[2], lo.u[2]);
            unpack2(b.u[2], b.u[3], hi.u[3], lo.u[3]);
            *(s8v*)&KhS[row * 72 + dc] = hi.v;
            *(s8v*)&KlS[row * 72 + dc] = lo.v;
        }
        // ---- stage V tile (SoA copy, pre-transposed in global) ----
        {
            int d  = t >> 2;
            int kc = (t & 3) * 8;
            size_t g = (size_t)bh * HD * SEQ + (size_t)d * SEQ + k0 + kc;
            int col = kc ^ (((d >> 3) & 3) << 3);
            *(s8v*)&VthS[d * 40 + col] = *(const s8v*)(Vth + g);
            *(s8v*)&VtlS[d * 40 + col] = *(const s8v*)(Vtl + g);
        }
        __syncthreads();

        // ---- QK^T: 16 q-rows x 32 keys per wave, split-bf16 ----
        f4v s0 = (f4v){0.f, 0.f, 0.f, 0.f};
        f4v s1 = (f4v){0.f, 0.f, 0.f, 0.f};
        {
            const u16* kb0 = KhS + l15 * 72 + quad * 8;
            const u16* lb0 = KlS + l15 * 72 + quad * 8;
            s8v kh0 = *(const s8v*)kb0, kh1 = *(const s8v*)(kb0 + 32);
            s8v kl0 = *(const s8v*)lb0, kl1 = *(const s8v*)(lb0 + 32);
            s0 = MFMA16(qh[0], kh0, s0); s0 = MFMA16(qh[1], kh1, s0);
            s0 = MFMA16(ql[0], kh0, s0); s0 = MFMA16(ql[1], kh1, s0);
            s0 = MFMA16(qh[0], kl0, s0); s0 = MFMA16(qh[1], kl1, s0);
            const u16* kb1 = KhS + (16 + l15) * 72 + quad * 8;
            const u16* lb1 = KlS + (16 + l15) * 72 + quad * 8;
            s8v kh2 = *(const s8v*)kb1, kh3 = *(const s8v*)(kb1 + 32);
            s8v kl2 = *(const s8v*)lb1, kl3 = *(const s8v*)(lb1 + 32);
            s1 = MFMA16(qh[0], kh2, s1); s1 = MFMA16(qh[1], kh3, s1);
            s1 = MFMA16(ql[0], kh2, s1); s1 = MFMA16(ql[1], kh3, s1);
            s1 = MFMA16(qh[0], kl2, s1); s1 = MFMA16(qh[1], kl3, s1);
        }

        // ---- static softmax: p = exp(s/8 - m0) ----
        #pragma unroll
        for (int r = 0; r < 4; r++) {
            float p0 = __expf(s0[r] * 0.125f - m0[r]);
            float p1 = __expf(s1[r] * 0.125f - m0[r]);
            lsum[r] += p0 + p1;

            int row_l = w * 16 + quad * 4 + r;
            int cs = row_l & 8;
            int c0 = l15 ^ cs;
            int c1 = (16 + l15) ^ cs;
            u16 h = f32_to_bf16(p0);
            PhS[row_l * 40 + c0] = h;
            PlS[row_l * 40 + c0] = f32_to_bf16(p0 - bf16_to_f32(h));
            h = f32_to_bf16(p1);
            PhS[row_l * 40 + c1] = h;
            PlS[row_l * 40 + c1] = f32_to_bf16(p1 - bf16_to_f32(h));
        }

        // ---- PV: split-bf16 ----
        {
            const int prow = w * 16 + l15;
            const u16* pb  = PhS + prow * 40 + ((quad * 8) ^ (prow & 8));
            const u16* plb = PlS + prow * 40 + ((quad * 8) ^ (prow & 8));
            s8v ph = *(const s8v*)pb;
            s8v pl = *(const s8v*)plb;
            #pragma unroll
            for (int nt = 0; nt < 4; nt++) {
                int dim = nt * 16 + l15;
                int voff = dim * 40 + ((quad * 8) ^ (((dim >> 3) & 3) << 3));
                s8v vh = *(const s8v*)&VthS[voff];
                s8v vl = *(const s8v*)&VtlS[voff];
                o[nt] = MFMA16(ph, vh, o[nt]);
                o[nt] = MFMA16(ph, vl, o[nt]);
                o[nt] = MFMA16(pl, vh, o[nt]);
            }
        }
    }

    // ---- epilogue: reduce l, normalize, write packed u32 (full sectors) ----
    const int b = bh >> 4;
    const int h = bh & 15;
    #pragma unroll
    for (int r = 0; r < 4; r++) {
        float l = lsum[r];
        l += __shfl_xor(l, 1, 64);
        l += __shfl_xor(l, 2, 64);
        l += __shfl_xor(l, 4, 64);
        l += __shfl_xor(l, 8, 64);
        float inv_l = 1.0f / l;
        int s = q0 + w * 16 + quad * 4 + r;
        size_t obase = (((size_t)b * SEQ + s) * NH + h) * HD;
        #pragma unroll
        for (int nt = 0; nt < 4; nt++) {
            AOp[obase + nt * 16 + l15] = pack_hl(o[nt][r] * inv_l);
        }
    }
}

// ---------------------------------------------------------------------------
// Out-projection GEMM: A = packed u32 AO (unpacked at fragment load),
// B = Wo hi/lo SoA. fp32 output.
// ---------------------------------------------------------------------------
__global__ __launch_bounds__(256, 2)
void gemm_out(const u32* __restrict__ Ap_g,
              const u16* __restrict__ Bh_g, const u16* __restrict__ Bl_g,
              const float* __restrict__ bias, float* __restrict__ out) {
    __shared__ u32 Ap[128 * 32];    // 16 KB (packed)
    __shared__ u16 Bh[128 * 32];    // 8 KB
    __shared__ u16 Bl[128 * 32];    // 8 KB

    const int t    = threadIdx.x;
    const int w    = t >> 6;
    const int lane = t & 63;
    const int quad = lane >> 4;
    const int l15  = lane & 15;
    const int wr   = w >> 1;
    const int wc   = w & 1;
    const int m0   = blockIdx.x * 128;
    const int n0   = blockIdx.y * 128;

    // A staging: 1024 slots of 16 B (4 u32); 8 slots per 128-row; 4 per thread
    const u32* agp = Ap_g + (size_t)(m0 + (t >> 3)) * KDIM + (t & 7) * 4;
    const size_t arow32 = (size_t)32 * KDIM;    // +32 rows per 256 slots
    // B staging (SoA u16): 512 slots per tile
    const int srow = t >> 2;
    const int scol = (t & 3) * 8;
    const u16* bgh = Bh_g + (size_t)(n0 + srow) * KDIM + scol;
    const u16* bgl = Bl_g + (size_t)(n0 + srow) * KDIM + scol;
    const size_t rstep = (size_t)64 * KDIM;

    f4v acc[4][4];
    #pragma unroll
    for (int i = 0; i < 4; i++)
        #pragma unroll
        for (int j = 0; j < 4; j++)
            acc[i][j] = (f4v){0.f, 0.f, 0.f, 0.f};

    for (int k0 = 0; k0 < KDIM; k0 += 32) {
        #pragma unroll
        for (int j = 0; j < 4; j++)
            ld16(agp + j * arow32 + k0, &Ap[(t + j * 256) * 4]);
        ld16(bgh + k0,         &Bh[t * 8]);
        ld16(bgh + rstep + k0, &Bh[(256 + t) * 8]);
        ld16(bgl + k0,         &Bl[t * 8]);
        ld16(bgl + rstep + k0, &Bl[(256 + t) * 8]);
        __syncthreads();

        union U8 { u32 u[4]; s8v v; };
        s8v ah[4], al[4], bh[4], bl[4];
        #pragma unroll
        for (int i = 0; i < 4; i++) {
            int ar = (wr * 64 + i * 16 + l15) * 32 + quad * 8;
            uint4 pa = *(const uint4*)&Ap[ar];
            uint4 pb = *(const uint4*)&Ap[ar + 4];
            U8 hi, lo;
            unpack2(pa.x, pa.y, hi.u[0], lo.u[0]);
            unpack2(pa.z, pa.w, hi.u[1], lo.u[1]);
            unpack2(pb.x, pb.y, hi.u[2], lo.u[2]);
            unpack2(pb.z, pb.w, hi.u[3], lo.u[3]);
            ah[i] = hi.v;
            al[i] = lo.v;
            int br = (wc * 64 + i * 16 + l15) * 32 + quad * 8;
            bh[i] = *(const s8v*)&Bh[br];
            bl[i] = *(const s8v*)&Bl[br];
        }
        #pragma unroll
        for (int mt = 0; mt < 4; mt++) {
            #pragma unroll
            for (int nt = 0; nt < 4; nt++) {
                acc[mt][nt] = MFMA16(ah[mt], bh[nt], acc[mt][nt]);
                acc[mt][nt] = MFMA16(ah[mt], bl[nt], acc[mt][nt]);
                acc[mt][nt] = MFMA16(al[mt], bh[nt], acc[mt][nt]);
            }
        }
        __syncthreads();
    }

    #pragma unroll
    for (int mt = 0; mt < 4; mt++) {
        #pragma unroll
        for (int nt = 0; nt < 4; nt++) {
            int n = n0 + wc * 64 + nt * 16 + l15;
            float bv = bias[n];
            #pragma unroll
            for (int r = 0; r < 4; r++) {
                int m = m0 + wr * 64 + mt * 16 + quad * 4 + r;
                out[(size_t)m * 1024 + n] = acc[mt][nt][r] + bv;
            }
        }
    }
}

// ---------------------------------------------------------------------------
extern "C" void kernel_launch(void* const* d_in, const int* in_sizes, int n_in,
                              void* d_out, int out_size, void* d_ws, size_t ws_size,
                              hipStream_t stream) {
    const float* x  = (const float*)d_in[0];
    const float* Wq = (const float*)d_in[1];
    const float* bq = (const float*)d_in[2];
    const float* Wk = (const float*)d_in[3];
    const float* bk = (const float*)d_in[4];
    const float* Wv = (const float*)d_in[5];
    const float* bv = (const float*)d_in[6];
    const float* Wo = (const float*)d_in[7];
    const float* bo = (const float*)d_in[8];
    float* out = (float*)d_out;

    const size_t TEN = (size_t)MROWS * KDIM;     // 4,194,304
    const size_t WSZ = (size_t)KDIM * KDIM;      // 1,048,576

    u16* xh  = (u16*)d_ws;
    u16* xl  = xh + TEN;
    u16* Wqh = xl + TEN;
    u16* Wql = Wqh + WSZ;
    u16* Wkh = Wql + WSZ;
    u16* Wkl = Wkh + WSZ;
    u16* Wvh = Wkl + WSZ;
    u16* Wvl = Wvh + WSZ;
    u16* Woh = Wvl + WSZ;
    u16* Wol = Woh + WSZ;
    u32* Qp  = (u32*)(Wol + WSZ);
    u32* Kp  = Qp + TEN;
    u16* Vth = (u16*)(Kp + TEN);
    u16* Vtl = Vth + TEN;
    // dead-buffer reuse: AOp <- x hi/lo region (16 MB); km2 <- Wvh
    u32* AOp = (u32*)xh;
    float* km2 = (float*)Wvh;

    convert_hl<<<8192, 256, 0, stream>>>(x, Wq, Wk, Wv, Wo,
                                         xh, xl, Wqh, Wql, Wkh, Wkl,
                                         Wvh, Wvl, Woh, Wol);

    qkv_gemm<<<dim3(32, 24), 256, 0, stream>>>(xh, xl, Wqh, Wql, Wkh, Wkl,
                                               Wvh, Wvl, bq, bk, bv,
                                               Qp, Kp, Vth, Vtl);

    hipMemsetAsync(km2, 0, 4, stream);
    kmax_kernel<<<1024, 256, 0, stream>>>(Kp, km2);

    flash_attn<<<dim3(SEQ / 64, BATCH * NH), 256, 0, stream>>>(
        Qp, Kp, Vth, Vtl, km2, AOp);

    gemm_out<<<dim3(MROWS / 128, KDIM / 128), 256, 0, stream>>>(
        AOp, Woh, Wol, bo, out);
}

// Round 6
// 429.616 us; speedup vs baseline: 5.3583x; 1.3375x over previous
//
#include <hip/hip_runtime.h>
#include <hip/hip_fp16.h>
#include <math.h>

#define D_MODEL 1024
#define NH 16
#define HD 64
#define SEQ 2048
#define BATCH 2
#define MROWS (BATCH*SEQ)   // 4096
#define KDIM 1024

typedef unsigned short u16;
typedef unsigned int u32;
typedef __attribute__((ext_vector_type(8))) _Float16 h8;   // 8 f16 (4 VGPRs)
typedef __attribute__((ext_vector_type(8))) short s8v;
typedef __attribute__((ext_vector_type(4))) float f4v;

#define MFMAH(a, b, c) __builtin_amdgcn_mfma_f32_16x16x32_f16(a, b, c, 0, 0, 0)

__device__ __forceinline__ u16 f32_to_f16(float f) {
    return __half_as_ushort(__float2half(f));   // v_cvt_f16_f32, RNE
}
__device__ __forceinline__ float f16_to_f32(u16 h) {
    return __half2float(__ushort_as_half(h));
}

// async global->LDS, 16 B per lane (global_load_lds_dwordx4)
__device__ __forceinline__ void ld16(const void* g, void* l) {
    __builtin_amdgcn_global_load_lds(
        (const __attribute__((address_space(1))) void*)g,
        (__attribute__((address_space(3))) void*)l, 16, 0, 0);
}

// ---------------------------------------------------------------------------
// fp32 -> fp16 conversion for x (4M) + 4 W (1M each). 8 elems/thread.
// ---------------------------------------------------------------------------
__global__ __launch_bounds__(256)
void convert_f16(const float* __restrict__ x,
                 const float* __restrict__ Wq, const float* __restrict__ Wk,
                 const float* __restrict__ Wv, const float* __restrict__ Wo,
                 u16* __restrict__ xF,
                 u16* __restrict__ WqF, u16* __restrict__ WkF,
                 u16* __restrict__ WvF, u16* __restrict__ WoF) {
    int i = blockIdx.x * 256 + threadIdx.x;      // 0 .. 2^20-1 (8-elem groups)
    const float* src;
    u16* dst;
    int idx;
    if (i < (1 << 19)) {                          // x: 512K groups
        src = x; dst = xF; idx = i;
    } else {
        int j = i - (1 << 19);
        int w = j >> 17;                          // 128K groups per W
        idx = j & ((1 << 17) - 1);
        switch (w) {
            case 0:  src = Wq; dst = WqF; break;
            case 1:  src = Wk; dst = WkF; break;
            case 2:  src = Wv; dst = WvF; break;
            default: src = Wo; dst = WoF; break;
        }
    }
    float4 a = ((const float4*)src)[idx * 2];
    float4 b = ((const float4*)src)[idx * 2 + 1];
    ushort4 o0, o1;
    o0.x = f32_to_f16(a.x); o0.y = f32_to_f16(a.y);
    o0.z = f32_to_f16(a.z); o0.w = f32_to_f16(a.w);
    o1.x = f32_to_f16(b.x); o1.y = f32_to_f16(b.y);
    o1.z = f32_to_f16(b.z); o1.w = f32_to_f16(b.w);
    ((ushort4*)dst)[idx * 2]     = o0;
    ((ushort4*)dst)[idx * 2 + 1] = o1;
}

// ---------------------------------------------------------------------------
// Fused QKV fp16 MFMA GEMM. Grid (32, 24): y>>3 selects Q/K/V.
// 128x128 tile, BK=32, 4 waves, 16 MFMA/wave/iter, 16 KB staged/iter.
// Q,K: fused RoPE -> fp16 [B,H,S,D]. V: LDS transpose -> fp16 [B,H,D,S].
// ---------------------------------------------------------------------------
__global__ __launch_bounds__(256, 2)
void qkv_gemm(const u16* __restrict__ xF, const u16* __restrict__ WqF,
              const u16* __restrict__ WkF, const u16* __restrict__ WvF,
              const float* __restrict__ bq, const float* __restrict__ bk,
              const float* __restrict__ bv,
              u16* __restrict__ QF, u16* __restrict__ KF,
              u16* __restrict__ VtF) {
    __shared__ __align__(16) u16 SMEM[16384];   // 32 KB; K-loop uses first 16 KB
    u16* As = SMEM;                 // [128][32] f16
    u16* Bs = SMEM + 4096;

    const int t    = threadIdx.x;
    const int w    = t >> 6;
    const int lane = t & 63;
    const int quad = lane >> 4;
    const int l15  = lane & 15;
    const int wr   = w >> 1;
    const int wc   = w & 1;
    const int m0b  = blockIdx.x * 128;
    const int wsel = blockIdx.y >> 3;
    const int n0   = (blockIdx.y & 7) * 128;

    const u16* Bg;
    const float* bias;
    if (wsel == 0)      { Bg = WqF; bias = bq; }
    else if (wsel == 1) { Bg = WkF; bias = bk; }
    else                { Bg = WvF; bias = bv; }

    const int srow = t >> 2;            // 0..63
    const int scol = (t & 3) * 8;
    const u16* ag = xF + (size_t)(m0b + srow) * KDIM + scol;
    const u16* bg = Bg + (size_t)(n0 + srow) * KDIM + scol;
    const size_t rstep = (size_t)64 * KDIM;

    f4v acc[4][4];
    #pragma unroll
    for (int i = 0; i < 4; i++)
        #pragma unroll
        for (int j = 0; j < 4; j++)
            acc[i][j] = (f4v){0.f, 0.f, 0.f, 0.f};

    for (int k0 = 0; k0 < KDIM; k0 += 32) {
        ld16(ag + k0,         &As[t * 8]);
        ld16(ag + rstep + k0, &As[(256 + t) * 8]);
        ld16(bg + k0,         &Bs[t * 8]);
        ld16(bg + rstep + k0, &Bs[(256 + t) * 8]);
        __syncthreads();

        h8 a[4], b[4];
        #pragma unroll
        for (int i = 0; i < 4; i++) {
            a[i] = *(const h8*)&As[(wr * 64 + i * 16 + l15) * 32 + quad * 8];
            b[i] = *(const h8*)&Bs[(wc * 64 + i * 16 + l15) * 32 + quad * 8];
        }
        #pragma unroll
        for (int mt = 0; mt < 4; mt++)
            #pragma unroll
            for (int nt = 0; nt < 4; nt++)
                acc[mt][nt] = MFMAH(a[mt], b[nt], acc[mt][nt]);
        __syncthreads();
    }

    if (wsel < 2) {
        // ---- Q/K: fused RoPE, fp16 stores [B,H,S,D] ----
        u16* OF = (wsel == 0) ? QF : KF;
        #pragma unroll
        for (int mt = 0; mt < 4; mt++) {
            #pragma unroll
            for (int r = 0; r < 4; r++) {
                int m = m0b + wr * 64 + mt * 16 + quad * 4 + r;
                int b = m >> 11;
                int s = m & 2047;
                #pragma unroll
                for (int nt = 0; nt < 2; nt++) {
                    int n1 = n0 + wc * 64 + nt * 16 + l15;
                    int dd = n1 & 31;
                    float v1 = acc[mt][nt][r]     + bias[n1];
                    float v2 = acc[mt][nt + 2][r] + bias[n1 + 32];
                    // 10000^(-dd/32) = exp(-dd * ln(1e4)/32)
                    float inv = __expf(-(float)dd * 0.2878231366f);
                    float ang = (float)s * inv;
                    float c  = cosf(ang);
                    float sn = sinf(ang);
                    float r1 = v1 * c - v2 * sn;
                    float r2 = v2 * c + v1 * sn;
                    int h = n1 >> 6;
                    int d = n1 & 63;
                    size_t base = (((size_t)b * NH + h) * SEQ + s) << 6;
                    OF[base + d]      = f32_to_f16(r1);
                    OF[base + d + 32] = f32_to_f16(r2);
                }
            }
        }
    } else {
        // ---- V: transpose via LDS, fp16 [B,H,D,S], 16-B stores ----
        const int b  = m0b >> 11;
        const int s0 = m0b & 2047;
        const int h0 = (blockIdx.y & 7) * 2;
        __syncthreads();
        #pragma unroll
        for (int mt = 0; mt < 4; mt++) {
            #pragma unroll
            for (int nt = 0; nt < 4; nt++) {
                int n = wc * 64 + nt * 16 + l15;
                float bv_ = bias[n0 + n];
                #pragma unroll
                for (int r = 0; r < 4; r++) {
                    int m = wr * 64 + mt * 16 + quad * 4 + r;
                    float v = acc[mt][nt][r] + bv_;
                    SMEM[n * 128 + ((((m >> 3) ^ (n & 15))) << 3) + (m & 7)] = f32_to_f16(v);
                }
            }
        }
        __syncthreads();
        int n = t >> 1;
        int half = t & 1;
        int d  = n & 63;
        int hh = n >> 6;
        size_t obase = ((size_t)((b * NH + h0 + hh) * HD + d)) * SEQ + s0;
        #pragma unroll
        for (int c = 0; c < 8; c++) {
            int mc = half * 8 + c;
            s8v val = *(const s8v*)&SMEM[n * 128 + ((mc ^ (n & 15)) << 3)];
            *(s8v*)(VtF + obase + mc * 8) = val;
        }
    }
}

// ---------------------------------------------------------------------------
// Global max of per-row K norm^2 (rows = B*NH*SEQ, 64 dims). 4 threads/row.
// ---------------------------------------------------------------------------
__global__ __launch_bounds__(256)
void kmax_kernel(const u16* __restrict__ KF, float* __restrict__ kmax2) {
    int gid = blockIdx.x * 256 + threadIdx.x;
    int row = gid >> 2, part = gid & 3;
    const u16* kp = KF + (size_t)row * 64 + part * 16;
    s8v a = *(const s8v*)kp;
    s8v b = *(const s8v*)(kp + 8);
    float sum = 0.f;
    #pragma unroll
    for (int e = 0; e < 8; e++) {
        float v0 = f16_to_f32((u16)a[e]);
        float v1 = f16_to_f32((u16)b[e]);
        sum += v0 * v0 + v1 * v1;
    }
    sum += __shfl_xor(sum, 1, 64);
    sum += __shfl_xor(sum, 2, 64);   // full row norm^2 (replicated in 4 lanes)
    sum = fmaxf(sum, __shfl_xor(sum, 4, 64));
    sum = fmaxf(sum, __shfl_xor(sum, 8, 64));
    sum = fmaxf(sum, __shfl_xor(sum, 16, 64));
    sum = fmaxf(sum, __shfl_xor(sum, 32, 64));
    __shared__ float red[4];
    if ((threadIdx.x & 63) == 0) red[threadIdx.x >> 6] = sum;
    __syncthreads();
    if (threadIdx.x == 0) {
        float m = fmaxf(fmaxf(red[0], red[1]), fmaxf(red[2], red[3]));
        atomicMax((int*)kmax2, __float_as_int(m));
    }
}

// ---------------------------------------------------------------------------
// MFMA flash attention, fp16, static-bound softmax.
// Q,K fp16 [B,H,S,D]; V fp16 [B,H,D,S]. AO out fp16 [B,S,H,D].
// m0 = |q||k|max/8 >= all logits (Cauchy-Schwarz); p = exp(s-m0) in (0,1].
// ---------------------------------------------------------------------------
__global__ __launch_bounds__(256)
void flash_attn(const u16* __restrict__ QF, const u16* __restrict__ KF,
                const u16* __restrict__ VtF,
                const float* __restrict__ kmax2,
                u16* __restrict__ AOF) {
    __shared__ __align__(16) u16 KS[32 * 72];
    __shared__ __align__(16) u16 VtS[64 * 40];
    __shared__ __align__(16) u16 PS[64 * 40];

    const int t    = threadIdx.x;
    const int w    = t >> 6;
    const int lane = t & 63;
    const int quad = lane >> 4;
    const int l15  = lane & 15;

    const int q0 = blockIdx.x * 64;
    const int bh = blockIdx.y;
    const size_t kvbase = (size_t)bh * SEQ * HD;

    // ---- Q fragments (held in registers) ----
    h8 qf[2];
    {
        const u16* qp = QF + kvbase + (size_t)(q0 + w * 16 + l15) * HD + quad * 8;
        qf[0] = *(const h8*)qp;
        qf[1] = *(const h8*)(qp + 32);
    }
    // row norm^2 of q
    float qn2 = 0.f;
    #pragma unroll
    for (int st = 0; st < 2; st++)
        #pragma unroll
        for (int e = 0; e < 8; e++) {
            float v = (float)qf[st][e];
            qn2 += v * v;
        }
    qn2 += __shfl_xor(qn2, 16, 64);
    qn2 += __shfl_xor(qn2, 32, 64);
    float km2 = kmax2[0];
    float m0[4];
    #pragma unroll
    for (int r = 0; r < 4; r++) {
        int src = (lane & 48) | (quad * 4 + r);
        float qr = __shfl(qn2, src, 64);
        m0[r] = sqrtf(qr * km2) * 0.125f;
    }

    f4v o[4];
    #pragma unroll
    for (int nt = 0; nt < 4; nt++) o[nt] = (f4v){0.f, 0.f, 0.f, 0.f};
    float lsum[4] = {0.f, 0.f, 0.f, 0.f};

    for (int k0 = 0; k0 < SEQ; k0 += 32) {
        __syncthreads();

        // ---- stage K tile (32 keys x 64 d) ----
        {
            int row = t >> 3;
            int dc  = (t & 7) * 8;
            *(s8v*)&KS[row * 72 + dc] =
                *(const s8v*)(KF + kvbase + (size_t)(k0 + row) * HD + dc);
        }
        // ---- stage V tile (64 d x 32 keys, pre-transposed, swizzled) ----
        {
            int d  = t >> 2;
            int kc = (t & 3) * 8;
            size_t g = (size_t)bh * HD * SEQ + (size_t)d * SEQ + k0 + kc;
            int col = kc ^ (((d >> 3) & 3) << 3);
            *(s8v*)&VtS[d * 40 + col] = *(const s8v*)(VtF + g);
        }
        __syncthreads();

        // ---- QK^T: 16 q-rows x 32 keys per wave ----
        f4v s0 = (f4v){0.f, 0.f, 0.f, 0.f};
        f4v s1 = (f4v){0.f, 0.f, 0.f, 0.f};
        {
            const u16* kb0 = KS + l15 * 72 + quad * 8;
            s0 = MFMAH(qf[0], *(const h8*)kb0, s0);
            s0 = MFMAH(qf[1], *(const h8*)(kb0 + 32), s0);
            const u16* kb1 = KS + (16 + l15) * 72 + quad * 8;
            s1 = MFMAH(qf[0], *(const h8*)kb1, s1);
            s1 = MFMAH(qf[1], *(const h8*)(kb1 + 32), s1);
        }

        // ---- static softmax: p = exp(s/8 - m0) ----
        #pragma unroll
        for (int r = 0; r < 4; r++) {
            float p0 = __expf(s0[r] * 0.125f - m0[r]);
            float p1 = __expf(s1[r] * 0.125f - m0[r]);
            lsum[r] += p0 + p1;

            int row_l = w * 16 + quad * 4 + r;
            int cs = row_l & 8;
            PS[row_l * 40 + (l15 ^ cs)]        = f32_to_f16(p0);
            PS[row_l * 40 + ((16 + l15) ^ cs)] = f32_to_f16(p1);
        }

        // ---- PV ----
        {
            const int prow = w * 16 + l15;
            h8 ph = *(const h8*)&PS[prow * 40 + ((quad * 8) ^ (prow & 8))];
            #pragma unroll
            for (int nt = 0; nt < 4; nt++) {
                int dim = nt * 16 + l15;
                int voff = dim * 40 + ((quad * 8) ^ (((dim >> 3) & 3) << 3));
                o[nt] = MFMAH(ph, *(const h8*)&VtS[voff], o[nt]);
            }
        }
    }

    // ---- epilogue: reduce l, normalize, write fp16 [B,S,H,D] ----
    const int b = bh >> 4;
    const int h = bh & 15;
    #pragma unroll
    for (int r = 0; r < 4; r++) {
        float l = lsum[r];
        l += __shfl_xor(l, 1, 64);
        l += __shfl_xor(l, 2, 64);
        l += __shfl_xor(l, 4, 64);
        l += __shfl_xor(l, 8, 64);
        float inv_l = 1.0f / l;
        int s = q0 + w * 16 + quad * 4 + r;
        size_t obase = (((size_t)b * SEQ + s) * NH + h) * HD;
        #pragma unroll
        for (int nt = 0; nt < 4; nt++) {
            AOF[obase + nt * 16 + l15] = f32_to_f16(o[nt][r] * inv_l);
        }
    }
}

// ---------------------------------------------------------------------------
// Out-projection fp16 MFMA GEMM, fp32 output [m*1024 + n].
// ---------------------------------------------------------------------------
__global__ __launch_bounds__(256, 2)
void gemm_out(const u16* __restrict__ AF, const u16* __restrict__ BF,
              const float* __restrict__ bias, float* __restrict__ out) {
    __shared__ __align__(16) u16 As[128 * 32];
    __shared__ __align__(16) u16 Bs[128 * 32];

    const int t    = threadIdx.x;
    const int w    = t >> 6;
    const int lane = t & 63;
    const int quad = lane >> 4;
    const int l15  = lane & 15;
    const int wr   = w >> 1;
    const int wc   = w & 1;
    const int m0   = blockIdx.x * 128;
    const int n0   = blockIdx.y * 128;

    const int srow = t >> 2;
    const int scol = (t & 3) * 8;
    const u16* ag = AF + (size_t)(m0 + srow) * KDIM + scol;
    const u16* bg = BF + (size_t)(n0 + srow) * KDIM + scol;
    const size_t rstep = (size_t)64 * KDIM;

    f4v acc[4][4];
    #pragma unroll
    for (int i = 0; i < 4; i++)
        #pragma unroll
        for (int j = 0; j < 4; j++)
            acc[i][j] = (f4v){0.f, 0.f, 0.f, 0.f};

    for (int k0 = 0; k0 < KDIM; k0 += 32) {
        ld16(ag + k0,         &As[t * 8]);
        ld16(ag + rstep + k0, &As[(256 + t) * 8]);
        ld16(bg + k0,         &Bs[t * 8]);
        ld16(bg + rstep + k0, &Bs[(256 + t) * 8]);
        __syncthreads();

        h8 a[4], b[4];
        #pragma unroll
        for (int i = 0; i < 4; i++) {
            a[i] = *(const h8*)&As[(wr * 64 + i * 16 + l15) * 32 + quad * 8];
            b[i] = *(const h8*)&Bs[(wc * 64 + i * 16 + l15) * 32 + quad * 8];
        }
        #pragma unroll
        for (int mt = 0; mt < 4; mt++)
            #pragma unroll
            for (int nt = 0; nt < 4; nt++)
                acc[mt][nt] = MFMAH(a[mt], b[nt], acc[mt][nt]);
        __syncthreads();
    }

    #pragma unroll
    for (int mt = 0; mt < 4; mt++) {
        #pragma unroll
        for (int nt = 0; nt < 4; nt++) {
            int n = n0 + wc * 64 + nt * 16 + l15;
            float bv = bias[n];
            #pragma unroll
            for (int r = 0; r < 4; r++) {
                int m = m0 + wr * 64 + mt * 16 + quad * 4 + r;
                out[(size_t)m * 1024 + n] = acc[mt][nt][r] + bv;
            }
        }
    }
}

// ---------------------------------------------------------------------------
extern "C" void kernel_launch(void* const* d_in, const int* in_sizes, int n_in,
                              void* d_out, int out_size, void* d_ws, size_t ws_size,
                              hipStream_t stream) {
    const float* x  = (const float*)d_in[0];
    const float* Wq = (const float*)d_in[1];
    const float* bq = (const float*)d_in[2];
    const float* Wk = (const float*)d_in[3];
    const float* bk = (const float*)d_in[4];
    const float* Wv = (const float*)d_in[5];
    const float* bv = (const float*)d_in[6];
    const float* Wo = (const float*)d_in[7];
    const float* bo = (const float*)d_in[8];
    float* out = (float*)d_out;

    const size_t TEN = (size_t)MROWS * KDIM;     // 4,194,304
    const size_t WSZ = (size_t)KDIM * KDIM;      // 1,048,576

    u16* xF  = (u16*)d_ws;
    u16* WqF = xF + TEN;
    u16* WkF = WqF + WSZ;
    u16* WvF = WkF + WSZ;
    u16* WoF = WvF + WSZ;
    u16* QF  = WoF + WSZ;
    u16* KF  = QF + TEN;
    u16* VtF = KF + TEN;
    float* km2 = (float*)(VtF + TEN);
    u16* AOF = xF;          // x dead after qkv_gemm

    convert_f16<<<4096, 256, 0, stream>>>(x, Wq, Wk, Wv, Wo,
                                          xF, WqF, WkF, WvF, WoF);

    qkv_gemm<<<dim3(32, 24), 256, 0, stream>>>(xF, WqF, WkF, WvF,
                                               bq, bk, bv, QF, KF, VtF);

    hipMemsetAsync(km2, 0, 4, stream);
    kmax_kernel<<<1024, 256, 0, stream>>>(KF, km2);

    flash_attn<<<dim3(SEQ / 64, BATCH * NH), 256, 0, stream>>>(
        QF, KF, VtF, km2, AOF);

    gemm_out<<<dim3(MROWS / 128, KDIM / 128), 256, 0, stream>>>(
        AOF, WoF, bo, out);
}

// Round 7
// 410.184 us; speedup vs baseline: 5.6121x; 1.0474x over previous
//
#include <hip/hip_runtime.h>
#include <hip/hip_fp16.h>
#include <math.h>

#define D_MODEL 1024
#define NH 16
#define HD 64
#define SEQ 2048
#define BATCH 2
#define MROWS (BATCH*SEQ)   // 4096
#define KDIM 1024

typedef unsigned short u16;
typedef unsigned int u32;
typedef __attribute__((ext_vector_type(8))) _Float16 h8;   // 8 f16 (4 VGPRs)
typedef __attribute__((ext_vector_type(8))) short s8v;
typedef __attribute__((ext_vector_type(4))) float f4v;

#define MFMAH(a, b, c) __builtin_amdgcn_mfma_f32_16x16x32_f16(a, b, c, 0, 0, 0)

__device__ __forceinline__ u16 f32_to_f16(float f) {
    return __half_as_ushort(__float2half(f));   // v_cvt_f16_f32, RNE
}
__device__ __forceinline__ float f16_to_f32(u16 h) {
    return __half2float(__ushort_as_half(h));
}

// async global->LDS, 16 B per lane (kept ONLY in gemm_out as the control)
__device__ __forceinline__ void ld16(const void* g, void* l) {
    __builtin_amdgcn_global_load_lds(
        (const __attribute__((address_space(1))) void*)g,
        (__attribute__((address_space(3))) void*)l, 16, 0, 0);
}

// ---------------------------------------------------------------------------
// fp32 -> fp16 conversion for x (4M) + 4 W (1M each). 8 elems/thread.
// ---------------------------------------------------------------------------
__global__ __launch_bounds__(256)
void convert_f16(const float* __restrict__ x,
                 const float* __restrict__ Wq, const float* __restrict__ Wk,
                 const float* __restrict__ Wv, const float* __restrict__ Wo,
                 u16* __restrict__ xF,
                 u16* __restrict__ WqF, u16* __restrict__ WkF,
                 u16* __restrict__ WvF, u16* __restrict__ WoF) {
    int i = blockIdx.x * 256 + threadIdx.x;
    const float* src;
    u16* dst;
    int idx;
    if (i < (1 << 19)) {
        src = x; dst = xF; idx = i;
    } else {
        int j = i - (1 << 19);
        int w = j >> 17;
        idx = j & ((1 << 17) - 1);
        switch (w) {
            case 0:  src = Wq; dst = WqF; break;
            case 1:  src = Wk; dst = WkF; break;
            case 2:  src = Wv; dst = WvF; break;
            default: src = Wo; dst = WoF; break;
        }
    }
    float4 a = ((const float4*)src)[idx * 2];
    float4 b = ((const float4*)src)[idx * 2 + 1];
    ushort4 o0, o1;
    o0.x = f32_to_f16(a.x); o0.y = f32_to_f16(a.y);
    o0.z = f32_to_f16(a.z); o0.w = f32_to_f16(a.w);
    o1.x = f32_to_f16(b.x); o1.y = f32_to_f16(b.y);
    o1.z = f32_to_f16(b.z); o1.w = f32_to_f16(b.w);
    ((ushort4*)dst)[idx * 2]     = o0;
    ((ushort4*)dst)[idx * 2 + 1] = o1;
}

// ---------------------------------------------------------------------------
// Fused QKV fp16 MFMA GEMM — EXPLICIT staging (no global_load_lds; ld16-vs-
// explicit A/B experiment: gemm_out keeps ld16). Grid (32, 24).
// Q,K: fused RoPE -> fp16 [B,H,S,D]. K also reduces max row-norm^2 (RoPE is a
// rotation, norm-invariant) -> atomicMax into km2. V: LDS transpose -> [B,H,D,S].
// ---------------------------------------------------------------------------
__global__ __launch_bounds__(256, 2)
void qkv_gemm(const u16* __restrict__ xF, const u16* __restrict__ WqF,
              const u16* __restrict__ WkF, const u16* __restrict__ WvF,
              const float* __restrict__ bq, const float* __restrict__ bk,
              const float* __restrict__ bv,
              u16* __restrict__ QF, u16* __restrict__ KF,
              u16* __restrict__ VtF, float* __restrict__ km2) {
    __shared__ __align__(16) u16 SMEM[16384];   // 32 KB; K-loop uses first 16 KB
    u16* As = SMEM;                 // [128][32] f16
    u16* Bs = SMEM + 4096;

    const int t    = threadIdx.x;
    const int w    = t >> 6;
    const int lane = t & 63;
    const int quad = lane >> 4;
    const int l15  = lane & 15;
    const int wr   = w >> 1;
    const int wc   = w & 1;
    const int m0b  = blockIdx.x * 128;
    const int wsel = blockIdx.y >> 3;
    const int n0   = (blockIdx.y & 7) * 128;

    const u16* Bg;
    const float* bias;
    if (wsel == 0)      { Bg = WqF; bias = bq; }
    else if (wsel == 1) { Bg = WkF; bias = bk; }
    else                { Bg = WvF; bias = bv; }

    const int srow = t >> 2;            // 0..63
    const int scol = (t & 3) * 8;
    const u16* ag = xF + (size_t)(m0b + srow) * KDIM + scol;
    const u16* bg = Bg + (size_t)(n0 + srow) * KDIM + scol;
    const size_t rstep = (size_t)64 * KDIM;

    f4v acc[4][4];
    #pragma unroll
    for (int i = 0; i < 4; i++)
        #pragma unroll
        for (int j = 0; j < 4; j++)
            acc[i][j] = (f4v){0.f, 0.f, 0.f, 0.f};

    for (int k0 = 0; k0 < KDIM; k0 += 32) {
        // explicit global loads (issued before the barrier; latency overlaps)
        s8v a0 = *(const s8v*)(ag + k0);
        s8v a1 = *(const s8v*)(ag + rstep + k0);
        s8v b0 = *(const s8v*)(bg + k0);
        s8v b1 = *(const s8v*)(bg + rstep + k0);
        __syncthreads();                 // prior iter's ds_reads done
        *(s8v*)&As[t * 8]         = a0;
        *(s8v*)&As[(256 + t) * 8] = a1;
        *(s8v*)&Bs[t * 8]         = b0;
        *(s8v*)&Bs[(256 + t) * 8] = b1;
        __syncthreads();

        h8 a[4], b[4];
        #pragma unroll
        for (int i = 0; i < 4; i++) {
            a[i] = *(const h8*)&As[(wr * 64 + i * 16 + l15) * 32 + quad * 8];
            b[i] = *(const h8*)&Bs[(wc * 64 + i * 16 + l15) * 32 + quad * 8];
        }
        #pragma unroll
        for (int mt = 0; mt < 4; mt++)
            #pragma unroll
            for (int nt = 0; nt < 4; nt++)
                acc[mt][nt] = MFMAH(a[mt], b[nt], acc[mt][nt]);
    }

    if (wsel < 2) {
        // ---- Q/K: fused RoPE, fp16 stores [B,H,S,D]; K: fused max-norm ----
        u16* OF = (wsel == 0) ? QF : KF;
        float kn_max = 0.f;
        #pragma unroll
        for (int mt = 0; mt < 4; mt++) {
            #pragma unroll
            for (int r = 0; r < 4; r++) {
                int m = m0b + wr * 64 + mt * 16 + quad * 4 + r;
                int b = m >> 11;
                int s = m & 2047;
                float rowsum = 0.f;
                #pragma unroll
                for (int nt = 0; nt < 2; nt++) {
                    int n1 = n0 + wc * 64 + nt * 16 + l15;
                    int dd = n1 & 31;
                    float v1 = acc[mt][nt][r]     + bias[n1];
                    float v2 = acc[mt][nt + 2][r] + bias[n1 + 32];
                    // 10000^(-dd/32) = exp2(-dd * log2(1e4)/32)
                    float inv = __expf(-(float)dd * 0.2878231366f);
                    float ang = (float)s * inv;
                    float c  = cosf(ang);
                    float sn = sinf(ang);
                    float r1 = v1 * c - v2 * sn;
                    float r2 = v2 * c + v1 * sn;
                    rowsum += v1 * v1 + v2 * v2;     // norm is RoPE-invariant
                    int h = n1 >> 6;
                    int d = n1 & 63;
                    size_t base = (((size_t)b * NH + h) * SEQ + s) << 6;
                    OF[base + d]      = f32_to_f16(r1);
                    OF[base + d + 32] = f32_to_f16(r2);
                }
                if (wsel == 1) {
                    // reduce across the 16 l15 lanes (full 64-d row)
                    rowsum += __shfl_xor(rowsum, 1, 64);
                    rowsum += __shfl_xor(rowsum, 2, 64);
                    rowsum += __shfl_xor(rowsum, 4, 64);
                    rowsum += __shfl_xor(rowsum, 8, 64);
                    kn_max = fmaxf(kn_max, rowsum);
                }
            }
        }
        if (wsel == 1) {
            kn_max = fmaxf(kn_max, __shfl_xor(kn_max, 16, 64));
            kn_max = fmaxf(kn_max, __shfl_xor(kn_max, 32, 64));
            if (lane == 0) atomicMax((int*)km2, __float_as_int(kn_max));
        }
    } else {
        // ---- V: transpose via LDS, fp16 [B,H,D,S], 16-B stores ----
        const int b  = m0b >> 11;
        const int s0 = m0b & 2047;
        const int h0 = (blockIdx.y & 7) * 2;
        __syncthreads();
        #pragma unroll
        for (int mt = 0; mt < 4; mt++) {
            #pragma unroll
            for (int nt = 0; nt < 4; nt++) {
                int n = wc * 64 + nt * 16 + l15;
                float bv_ = bias[n0 + n];
                #pragma unroll
                for (int r = 0; r < 4; r++) {
                    int m = wr * 64 + mt * 16 + quad * 4 + r;
                    float v = acc[mt][nt][r] + bv_;
                    SMEM[n * 128 + ((((m >> 3) ^ (n & 15))) << 3) + (m & 7)] = f32_to_f16(v);
                }
            }
        }
        __syncthreads();
        int n = t >> 1;
        int half = t & 1;
        int d  = n & 63;
        int hh = n >> 6;
        size_t obase = ((size_t)((b * NH + h0 + hh) * HD + d)) * SEQ + s0;
        #pragma unroll
        for (int c = 0; c < 8; c++) {
            int mc = half * 8 + c;
            s8v val = *(const s8v*)&SMEM[n * 128 + ((mc ^ (n & 15)) << 3)];
            *(s8v*)(VtF + obase + mc * 8) = val;
        }
    }
}

// ---------------------------------------------------------------------------
// MFMA flash attention, fp16, static-bound softmax, Q-TILE 128 (2 row-tiles
// per wave -> K/V staged half as often, 16 MFMA per staging iteration).
// Q,K fp16 [B,H,S,D]; V fp16 [B,H,D,S]. AO out fp16 [B,S,H,D].
// ---------------------------------------------------------------------------
__global__ __launch_bounds__(256, 4)
void flash_attn(const u16* __restrict__ QF, const u16* __restrict__ KF,
                const u16* __restrict__ VtF,
                const float* __restrict__ kmax2,
                u16* __restrict__ AOF) {
    __shared__ __align__(16) u16 KS[32 * 72];
    __shared__ __align__(16) u16 VtS[64 * 40];
    __shared__ __align__(16) u16 PS[128 * 40];

    const int t    = threadIdx.x;
    const int w    = t >> 6;
    const int lane = t & 63;
    const int quad = lane >> 4;
    const int l15  = lane & 15;

    const int q0 = blockIdx.x * 128;
    const int bh = blockIdx.y;
    const size_t kvbase = (size_t)bh * SEQ * HD;
    const float km2 = kmax2[0];

    // ---- Q fragments for both row-tiles; static softmax bounds ----
    h8 qf[2][2];
    float m0[2][4];
    #pragma unroll
    for (int g = 0; g < 2; g++) {
        const u16* qp = QF + kvbase +
            (size_t)(q0 + g * 64 + w * 16 + l15) * HD + quad * 8;
        qf[g][0] = *(const h8*)qp;
        qf[g][1] = *(const h8*)(qp + 32);
        float qn2 = 0.f;
        #pragma unroll
        for (int st = 0; st < 2; st++)
            #pragma unroll
            for (int e = 0; e < 8; e++) {
                float v = (float)qf[g][st][e];
                qn2 += v * v;
            }
        qn2 += __shfl_xor(qn2, 16, 64);
        qn2 += __shfl_xor(qn2, 32, 64);
        #pragma unroll
        for (int r = 0; r < 4; r++) {
            int src = (lane & 48) | (quad * 4 + r);
            float qr = __shfl(qn2, src, 64);
            m0[g][r] = sqrtf(qr * km2) * 0.125f;
        }
    }

    f4v o[2][4];
    float lsum[2][4];
    #pragma unroll
    for (int g = 0; g < 2; g++)
        #pragma unroll
        for (int nt = 0; nt < 4; nt++) {
            o[g][nt] = (f4v){0.f, 0.f, 0.f, 0.f};
            lsum[g][nt] = 0.f;
        }

    for (int k0 = 0; k0 < SEQ; k0 += 32) {
        __syncthreads();

        // ---- stage K tile (32 keys x 64 d) ----
        {
            int row = t >> 3;
            int dc  = (t & 7) * 8;
            *(s8v*)&KS[row * 72 + dc] =
                *(const s8v*)(KF + kvbase + (size_t)(k0 + row) * HD + dc);
        }
        // ---- stage V tile (64 d x 32 keys, pre-transposed, swizzled) ----
        {
            int d  = t >> 2;
            int kc = (t & 3) * 8;
            size_t g = (size_t)bh * HD * SEQ + (size_t)d * SEQ + k0 + kc;
            int col = kc ^ (((d >> 3) & 3) << 3);
            *(s8v*)&VtS[d * 40 + col] = *(const s8v*)(VtF + g);
        }
        __syncthreads();

        const u16* kb0 = KS + l15 * 72 + quad * 8;
        const u16* kb1 = KS + (16 + l15) * 72 + quad * 8;
        h8 kh0 = *(const h8*)kb0, kh1 = *(const h8*)(kb0 + 32);
        h8 kh2 = *(const h8*)kb1, kh3 = *(const h8*)(kb1 + 32);

        #pragma unroll
        for (int g = 0; g < 2; g++) {
            // ---- QK^T: 16 q-rows x 32 keys ----
            f4v s0 = (f4v){0.f, 0.f, 0.f, 0.f};
            f4v s1 = (f4v){0.f, 0.f, 0.f, 0.f};
            s0 = MFMAH(qf[g][0], kh0, s0);
            s0 = MFMAH(qf[g][1], kh1, s0);
            s1 = MFMAH(qf[g][0], kh2, s1);
            s1 = MFMAH(qf[g][1], kh3, s1);

            // ---- static softmax: p = exp(s/8 - m0) ----
            #pragma unroll
            for (int r = 0; r < 4; r++) {
                float p0 = __expf(s0[r] * 0.125f - m0[g][r]);
                float p1 = __expf(s1[r] * 0.125f - m0[g][r]);
                lsum[g][r] += p0 + p1;
                int row_l = g * 64 + w * 16 + quad * 4 + r;
                int cs = row_l & 8;
                PS[row_l * 40 + (l15 ^ cs)]        = f32_to_f16(p0);
                PS[row_l * 40 + ((16 + l15) ^ cs)] = f32_to_f16(p1);
            }

            // ---- PV (P rows are wave-private; no barrier needed) ----
            const int prow = g * 64 + w * 16 + l15;
            h8 ph = *(const h8*)&PS[prow * 40 + ((quad * 8) ^ (prow & 8))];
            #pragma unroll
            for (int nt = 0; nt < 4; nt++) {
                int dim = nt * 16 + l15;
                int voff = dim * 40 + ((quad * 8) ^ (((dim >> 3) & 3) << 3));
                o[g][nt] = MFMAH(ph, *(const h8*)&VtS[voff], o[g][nt]);
            }
        }
    }

    // ---- epilogue: reduce l, normalize, write fp16 [B,S,H,D] ----
    const int b = bh >> 4;
    const int h = bh & 15;
    #pragma unroll
    for (int g = 0; g < 2; g++) {
        #pragma unroll
        for (int r = 0; r < 4; r++) {
            float l = lsum[g][r];
            l += __shfl_xor(l, 1, 64);
            l += __shfl_xor(l, 2, 64);
            l += __shfl_xor(l, 4, 64);
            l += __shfl_xor(l, 8, 64);
            float inv_l = 1.0f / l;
            int s = q0 + g * 64 + w * 16 + quad * 4 + r;
            size_t obase = (((size_t)b * SEQ + s) * NH + h) * HD;
            #pragma unroll
            for (int nt = 0; nt < 4; nt++) {
                AOF[obase + nt * 16 + l15] = f32_to_f16(o[g][nt][r] * inv_l);
            }
        }
    }
}

// ---------------------------------------------------------------------------
// Out-projection fp16 MFMA GEMM (UNCHANGED: keeps global_load_lds as control).
// ---------------------------------------------------------------------------
__global__ __launch_bounds__(256, 2)
void gemm_out(const u16* __restrict__ AF, const u16* __restrict__ BF,
              const float* __restrict__ bias, float* __restrict__ out) {
    __shared__ __align__(16) u16 As[128 * 32];
    __shared__ __align__(16) u16 Bs[128 * 32];

    const int t    = threadIdx.x;
    const int w    = t >> 6;
    const int lane = t & 63;
    const int quad = lane >> 4;
    const int l15  = lane & 15;
    const int wr   = w >> 1;
    const int wc   = w & 1;
    const int m0   = blockIdx.x * 128;
    const int n0   = blockIdx.y * 128;

    const int srow = t >> 2;
    const int scol = (t & 3) * 8;
    const u16* ag = AF + (size_t)(m0 + srow) * KDIM + scol;
    const u16* bg = BF + (size_t)(n0 + srow) * KDIM + scol;
    const size_t rstep = (size_t)64 * KDIM;

    f4v acc[4][4];
    #pragma unroll
    for (int i = 0; i < 4; i++)
        #pragma unroll
        for (int j = 0; j < 4; j++)
            acc[i][j] = (f4v){0.f, 0.f, 0.f, 0.f};

    for (int k0 = 0; k0 < KDIM; k0 += 32) {
        ld16(ag + k0,         &As[t * 8]);
        ld16(ag + rstep + k0, &As[(256 + t) * 8]);
        ld16(bg + k0,         &Bs[t * 8]);
        ld16(bg + rstep + k0, &Bs[(256 + t) * 8]);
        __syncthreads();

        h8 a[4], b[4];
        #pragma unroll
        for (int i = 0; i < 4; i++) {
            a[i] = *(const h8*)&As[(wr * 64 + i * 16 + l15) * 32 + quad * 8];
            b[i] = *(const h8*)&Bs[(wc * 64 + i * 16 + l15) * 32 + quad * 8];
        }
        #pragma unroll
        for (int mt = 0; mt < 4; mt++)
            #pragma unroll
            for (int nt = 0; nt < 4; nt++)
                acc[mt][nt] = MFMAH(a[mt], b[nt], acc[mt][nt]);
        __syncthreads();
    }

    #pragma unroll
    for (int mt = 0; mt < 4; mt++) {
        #pragma unroll
        for (int nt = 0; nt < 4; nt++) {
            int n = n0 + wc * 64 + nt * 16 + l15;
            float bv = bias[n];
            #pragma unroll
            for (int r = 0; r < 4; r++) {
                int m = m0 + wr * 64 + mt * 16 + quad * 4 + r;
                out[(size_t)m * 1024 + n] = acc[mt][nt][r] + bv;
            }
        }
    }
}

// ---------------------------------------------------------------------------
extern "C" void kernel_launch(void* const* d_in, const int* in_sizes, int n_in,
                              void* d_out, int out_size, void* d_ws, size_t ws_size,
                              hipStream_t stream) {
    const float* x  = (const float*)d_in[0];
    const float* Wq = (const float*)d_in[1];
    const float* bq = (const float*)d_in[2];
    const float* Wk = (const float*)d_in[3];
    const float* bk = (const float*)d_in[4];
    const float* Wv = (const float*)d_in[5];
    const float* bv = (const float*)d_in[6];
    const float* Wo = (const float*)d_in[7];
    const float* bo = (const float*)d_in[8];
    float* out = (float*)d_out;

    const size_t TEN = (size_t)MROWS * KDIM;     // 4,194,304
    const size_t WSZ = (size_t)KDIM * KDIM;      // 1,048,576

    u16* xF  = (u16*)d_ws;
    u16* WqF = xF + TEN;
    u16* WkF = WqF + WSZ;
    u16* WvF = WkF + WSZ;
    u16* WoF = WvF + WSZ;
    u16* QF  = WoF + WSZ;
    u16* KF  = QF + TEN;
    u16* VtF = KF + TEN;
    float* km2 = (float*)(VtF + TEN);
    u16* AOF = xF;          // x dead after qkv_gemm

    convert_f16<<<4096, 256, 0, stream>>>(x, Wq, Wk, Wv, Wo,
                                          xF, WqF, WkF, WvF, WoF);

    hipMemsetAsync(km2, 0, 4, stream);

    qkv_gemm<<<dim3(32, 24), 256, 0, stream>>>(xF, WqF, WkF, WvF,
                                               bq, bk, bv, QF, KF, VtF, km2);

    flash_attn<<<dim3(SEQ / 128, BATCH * NH), 256, 0, stream>>>(
        QF, KF, VtF, km2, AOF);

    gemm_out<<<dim3(MROWS / 128, KDIM / 128), 256, 0, stream>>>(
        AOF, WoF, bo, out);
}